// Round 5
// baseline (471.174 us; speedup 1.0000x reference)
//
#include <hip/hip_runtime.h>

// ---------------------------------------------------------------------------
// GraphSAGE 3-layer forward, MI355X.
//   CSR build: coarse 256-bucket histogram -> tiny scan -> part_scatter
//     (bucket-grouped int2 edges, dense writes) -> bucket_build (per-bucket
//     LDS count/scan/scatter -> offs + ssrc). No node-level global atomics.
//   Per layer: bf16 MFMA GEMM [y|z] = A @ [Wl;Wr].T (fp32 accum), 64x128
//     tiles; y quantized to per-row symmetric INT8 (excess-128) + fp32 row
//     scale; z bf16 (LN layers) / fp32 (final) keeps self-term full prec.
//   Aggregation: duration was pinned at ~69us across bf16/int8/2xMLP variants
//     => bound by divergent-gather ADDRESS count (TA), not bytes. Now 8
//     lanes x uint4 (16B) per edge (was 16 x 8B): addresses/edge halved,
//     decode VALU/edge quartered. agg_out64: 4 lanes x uint4 per edge.
// R11->R12: agg kernels restructured for 16B/lane gathers; GEMM/CSR as R11.
// ---------------------------------------------------------------------------

typedef __bf16 bf16x8 __attribute__((ext_vector_type(8)));
typedef __bf16 bf16x4 __attribute__((ext_vector_type(4)));
typedef float  f32x4  __attribute__((ext_vector_type(4)));

// accumulate 16 excess-128 u8 (uint4) scaled by s into acc[0..15]
__device__ __forceinline__ void u8_acc16(uint4 w, float s, float* acc) {
    acc[ 0] += s * (float)( w.x        & 0xffu);
    acc[ 1] += s * (float)((w.x >>  8) & 0xffu);
    acc[ 2] += s * (float)((w.x >> 16) & 0xffu);
    acc[ 3] += s * (float)( w.x >> 24        );
    acc[ 4] += s * (float)( w.y        & 0xffu);
    acc[ 5] += s * (float)((w.y >>  8) & 0xffu);
    acc[ 6] += s * (float)((w.y >> 16) & 0xffu);
    acc[ 7] += s * (float)( w.y >> 24        );
    acc[ 8] += s * (float)( w.z        & 0xffu);
    acc[ 9] += s * (float)((w.z >>  8) & 0xffu);
    acc[10] += s * (float)((w.z >> 16) & 0xffu);
    acc[11] += s * (float)( w.z >> 24        );
    acc[12] += s * (float)( w.w        & 0xffu);
    acc[13] += s * (float)((w.w >>  8) & 0xffu);
    acc[14] += s * (float)((w.w >> 16) & 0xffu);
    acc[15] += s * (float)( w.w >> 24        );
}

#define PB_SHIFT 9                      // 512 nodes per coarse bucket
#define PB_NB    256                    // covers N <= 131072
#define PB_EPT   8
#define PB_BLOCK 256
#define PB_CHUNK (PB_BLOCK * PB_EPT)    // 2048 edges per block

__global__ __launch_bounds__(PB_BLOCK) void coarse_hist(
    const int* __restrict__ dst, int* __restrict__ bhist, int E) {
    __shared__ int h[PB_NB];
    const int t = threadIdx.x;
    h[t] = 0;
    __syncthreads();
    const int e0 = blockIdx.x * PB_CHUNK + t;
#pragma unroll
    for (int i = 0; i < PB_EPT; ++i) {
        int e = e0 + i * PB_BLOCK;
        if (e < E) atomicAdd(&h[dst[e] >> PB_SHIFT], 1);
    }
    __syncthreads();
    if (h[t]) atomicAdd(&bhist[t], h[t]);
}

__global__ __launch_bounds__(PB_NB) void coarse_scan(
    const int* __restrict__ bhist, int* __restrict__ bbase, int* __restrict__ bcur) {
    __shared__ int sm[PB_NB];
    const int t = threadIdx.x;
    int v = bhist[t];
    sm[t] = v;
    __syncthreads();
    for (int off = 1; off < PB_NB; off <<= 1) {
        int add = (t >= off) ? sm[t - off] : 0;
        __syncthreads();
        sm[t] += add;
        __syncthreads();
    }
    int excl = sm[t] - v;
    bbase[t] = excl;
    bcur[t] = excl;
}

__global__ __launch_bounds__(PB_BLOCK) void part_scatter(
    const int* __restrict__ src, const int* __restrict__ dst,
    int* __restrict__ bcursor, int2* __restrict__ part, int E) {
    __shared__ int hist[PB_NB];
    __shared__ int base[PB_NB];
    const int t = threadIdx.x;
    hist[t] = 0;
    __syncthreads();
    const int e0 = blockIdx.x * PB_CHUNK + t;
    int my_s[PB_EPT], my_d[PB_EPT], my_r[PB_EPT];
#pragma unroll
    for (int i = 0; i < PB_EPT; ++i) {
        int e = e0 + i * PB_BLOCK;
        if (e < E) {
            my_s[i] = src[e];
            my_d[i] = dst[e];
            my_r[i] = atomicAdd(&hist[my_d[i] >> PB_SHIFT], 1);
        }
    }
    __syncthreads();
    {
        int c = hist[t];
        base[t] = c ? atomicAdd(&bcursor[t], c) : 0;
    }
    __syncthreads();
#pragma unroll
    for (int i = 0; i < PB_EPT; ++i) {
        int e = e0 + i * PB_BLOCK;
        if (e < E) {
            int b = my_d[i] >> PB_SHIFT;
            part[base[b] + my_r[i]] = make_int2(my_s[i], my_d[i]);
        }
    }
}

__global__ __launch_bounds__(256) void bucket_build(
    const int2* __restrict__ part, const int* __restrict__ bbase,
    int* __restrict__ offs, int* __restrict__ ssrc, int N, int E) {
    __shared__ int h[512];
    __shared__ int s[512];
    __shared__ int cur[512];
    const int b = blockIdx.x;
    const int t = threadIdx.x;
    const int beg = bbase[b];
    const int end = (b == PB_NB - 1) ? E : bbase[b + 1];

    h[t] = 0; h[t + 256] = 0;
    __syncthreads();
    for (int e = beg + t; e < end; e += 256)
        atomicAdd(&h[part[e].y & 511], 1);
    __syncthreads();
    s[t] = h[t]; s[t + 256] = h[t + 256];
    __syncthreads();
    for (int off = 1; off < 512; off <<= 1) {
        int a0 = (t >= off) ? s[t - off] : 0;
        int i1 = t + 256;
        int a1 = (i1 >= off) ? s[i1 - off] : 0;
        __syncthreads();
        s[t] += a0; s[i1] += a1;
        __syncthreads();
    }
#pragma unroll
    for (int k = 0; k < 2; ++k) {
        int i = t + k * 256;
        int excl = s[i] - h[i];
        cur[i] = excl;
        int node = (b << PB_SHIFT) + i;
        if (node < N) offs[node] = beg + excl;
    }
    if (b == 0 && t == 0) offs[N] = E;
    __syncthreads();
    for (int e = beg + t; e < end; e += 256) {
        int2 sd = part[e];
        int p = atomicAdd(&cur[sd.y & 511], 1);
        ssrc[beg + p] = sd.x;
    }
}

// ---------------------------------------------------------------------------
// MFMA GEMM: out cols = full DOUT of Wl (by=0 -> ybuf int8 + yscale) or Wr
// (by=1 -> zbuf + bias). 64 rows x DOUT cols per block, 4 waves each
// 32 x DOUT/2. K=128 LDS-resident (stride 136 bf16 -> 2-way alias, free).
// y epilogue: 16-lane |max| reduce -> LDS cross-wave rowmax -> s=rowmax/127,
// store u8 = rint(v/s)+128 and yscale[row]=s.
// ---------------------------------------------------------------------------
template <int DOUT, typename AT, typename ZT>
__global__ __launch_bounds__(256) void gemm_mfma(
    const AT* __restrict__ A,
    const float* __restrict__ Wl,
    const float* __restrict__ Wr,
    const float* __restrict__ bias,
    unsigned char* __restrict__ ybuf,   // [M][DOUT] u8 (excess-128)
    float*         __restrict__ yscale, // [M]
    ZT*            __restrict__ zbuf,
    int M) {
    __shared__ __bf16 Asm[64 * 136];
    __shared__ __bf16 Bsm[DOUT * 136];
    __shared__ float  rmx[2][64];

    const int t = threadIdx.x;
    const int rowBase = blockIdx.x * 64;
    const bool isZ = blockIdx.y != 0;
    const float* W = isZ ? Wr : Wl;

    if constexpr (sizeof(AT) == 4) {
#pragma unroll
        for (int i = 0; i < 8; ++i) {
            int idx = t + 256 * i;
            int r = idx >> 5;
            int c4 = idx & 31;
            int grow = rowBase + r;
            if (grow >= M) grow = M - 1;
            float4 v = *(const float4*)((const float*)A + (size_t)grow * 128 + c4 * 4);
            bf16x4 o;
            o[0] = (__bf16)v.x; o[1] = (__bf16)v.y; o[2] = (__bf16)v.z; o[3] = (__bf16)v.w;
            *(bf16x4*)(Asm + r * 136 + c4 * 4) = o;
        }
    } else {
#pragma unroll
        for (int i = 0; i < 4; ++i) {
            int idx = t + 256 * i;
            int r = idx >> 4;
            int c8 = idx & 15;
            int grow = rowBase + r;
            if (grow >= M) grow = M - 1;
            bf16x8 v = *(const bf16x8*)((const __bf16*)A + (size_t)grow * 128 + c8 * 8);
            *(bf16x8*)(Asm + r * 136 + c8 * 8) = v;
        }
    }
    constexpr int BCH = DOUT * 32 / 256;   // float4 chunks per thread
#pragma unroll
    for (int i = 0; i < BCH; ++i) {
        int idx = t + 256 * i;
        int r = idx >> 5;
        int c4 = idx & 31;
        float4 v = *(const float4*)(W + (size_t)r * 128 + c4 * 4);
        bf16x4 o;
        o[0] = (__bf16)v.x; o[1] = (__bf16)v.y; o[2] = (__bf16)v.z; o[3] = (__bf16)v.w;
        *(bf16x4*)(Bsm + r * 136 + c4 * 4) = o;
    }
    __syncthreads();

    const int lane = t & 63;
    const int wid = t >> 6;
    const int mb = (wid >> 1) * 32;              // row half
    const int nbase = (wid & 1) * (DOUT / 2);    // col half
    constexpr int NJ = DOUT / 32;                // 16-col tiles per wave
    const int ln = lane & 15;
    const int qk = lane >> 4;

    f32x4 acc[2][NJ] = {};
#pragma unroll
    for (int ks = 0; ks < 4; ++ks) {
        const int k0 = ks * 32 + qk * 8;
        bf16x8 a0 = *(const bf16x8*)(Asm + (mb + ln) * 136 + k0);
        bf16x8 a1 = *(const bf16x8*)(Asm + (mb + 16 + ln) * 136 + k0);
        bf16x8 b[NJ];
#pragma unroll
        for (int j = 0; j < NJ; ++j)
            b[j] = *(const bf16x8*)(Bsm + (nbase + j * 16 + ln) * 136 + k0);
#pragma unroll
        for (int j = 0; j < NJ; ++j) {
            acc[0][j] = __builtin_amdgcn_mfma_f32_16x16x32_bf16(a0, b[j], acc[0][j], 0, 0, 0);
            acc[1][j] = __builtin_amdgcn_mfma_f32_16x16x32_bf16(a1, b[j], acc[1][j], 0, 0, 0);
        }
    }

    // C/D: col = lane&15, row = (lane>>4)*4 + reg  [m89-verified]
    if (isZ) {
        float bcol[NJ];
#pragma unroll
        for (int j = 0; j < NJ; ++j) bcol[j] = bias[nbase + j * 16 + ln];
#pragma unroll
        for (int i = 0; i < 2; ++i) {
#pragma unroll
            for (int r = 0; r < 4; ++r) {
                int grow = rowBase + mb + i * 16 + qk * 4 + r;
                if (grow >= M) continue;
#pragma unroll
                for (int j = 0; j < NJ; ++j) {
                    int col = nbase + j * 16 + ln;
                    zbuf[(size_t)grow * DOUT + col] = (ZT)(acc[i][j][r] + bcol[j]);
                }
            }
        }
    } else {
        // per-row |max| over this wave's col-half, 16-lane butterfly
#pragma unroll
        for (int i = 0; i < 2; ++i) {
#pragma unroll
            for (int r = 0; r < 4; ++r) {
                float m = 0.f;
#pragma unroll
                for (int j = 0; j < NJ; ++j) m = fmaxf(m, fabsf(acc[i][j][r]));
#pragma unroll
                for (int o = 1; o < 16; o <<= 1) m = fmaxf(m, __shfl_xor(m, o, 64));
                if (ln == 0) rmx[wid & 1][mb + i * 16 + qk * 4 + r] = m;
            }
        }
        __syncthreads();
#pragma unroll
        for (int i = 0; i < 2; ++i) {
#pragma unroll
            for (int r = 0; r < 4; ++r) {
                int rb = mb + i * 16 + qk * 4 + r;
                int grow = rowBase + rb;
                if (grow >= M) continue;
                float rm = fmaxf(fmaxf(rmx[0][rb], rmx[1][rb]), 1e-20f);
                float sc = rm * (1.f / 127.f);
                float rs = 127.f / rm;
                if ((wid & 1) == 0 && ln == 0) yscale[grow] = sc;
#pragma unroll
                for (int j = 0; j < NJ; ++j) {
                    int col = nbase + j * 16 + ln;
                    float q = rintf(acc[i][j][r] * rs) + 128.f;
                    ybuf[(size_t)grow * DOUT + col] = (unsigned char)q;
                }
            }
        }
    }
}

// ---------------------------------------------------------------------------
// Aggregation 128f: one wave per node; 8 lanes x uint4 (16B) per edge ->
// 8 edges per gather instruction, 8 divergent addresses per edge (was 16).
// lane = g*8+f: g=edge slot, f=feature 16-tuple. Reduce over g = 3 butterfly
// levels. mean + z(bf16) -> ReLU -> LN (in-place, all-lane redundant) -> h.
// ---------------------------------------------------------------------------
__global__ __launch_bounds__(256) void agg_ln128(
    const int* __restrict__ offs, const int* __restrict__ ssrc,
    const unsigned char* __restrict__ ybuf,   // [N][128] u8
    const float* __restrict__ yscale,         // [N]
    const __bf16* __restrict__ zbuf,          // [N][128] bf16
    const float* __restrict__ gamma, const float* __restrict__ beta,
    __bf16* __restrict__ hout, int nNodes) {
    const int lane = threadIdx.x & 63;
    const int g = lane >> 3;          // edge slot 0..7
    const int f = lane & 7;           // feature 16-tuple 0..7
    const int node = blockIdx.x * 4 + (threadIdx.x >> 6);
    if (node >= nNodes) return;
    const int beg = offs[node], end = offs[node + 1];
    const int deg = end - beg;

    float acc[16] = {};
    float sS = 0.f;
    const int iters = (deg + 7) >> 3;            // 8 edges / iter
    int e = beg + g;
    int idx = 0;
    if (iters > 0) idx = ssrc[(e < end) ? e : beg];
    for (int u = 0; u < iters; ++u) {
        const bool v = e < end;
        uint4 w;
        if (v) w = *(const uint4*)(ybuf + (((unsigned)idx) << 7) + (f << 4));
        float s = yscale[idx];
        int e2 = e + 8;
        int idx2 = ssrc[(e2 < end) ? e2 : beg];   // prefetch next
        if (v) { u8_acc16(w, s, acc); sS += s; }
        e = e2; idx = idx2;
    }

    // epilogue loads before the butterfly to overlap latency
    bf16x8 zv0 = *(const bf16x8*)(zbuf + (size_t)node * 128 + f * 16);
    bf16x8 zv1 = *(const bf16x8*)(zbuf + (size_t)node * 128 + f * 16 + 8);

    sS += __shfl_xor(sS, 8, 64);
    sS += __shfl_xor(sS, 16, 64);
    sS += __shfl_xor(sS, 32, 64);
#pragma unroll
    for (int m = 0; m < 16; ++m) {
        acc[m] += __shfl_xor(acc[m], 8, 64);
        acc[m] += __shfl_xor(acc[m], 16, 64);
        acc[m] += __shfl_xor(acc[m], 32, 64);
    }
    const float inv = 1.f / (float)((deg > 1) ? deg : 1);
    const float bias128 = 128.f * sS;
#pragma unroll
    for (int m = 0; m < 16; ++m) {
        float z = (float)((m < 8) ? zv0[m & 7] : zv1[m & 7]);
        acc[m] = fmaxf((acc[m] - bias128) * inv + z, 0.f);   // v, in place
    }

    float s = 0.f;
#pragma unroll
    for (int m = 0; m < 16; ++m) s += acc[m];
    s += __shfl_xor(s, 1, 64);
    s += __shfl_xor(s, 2, 64);
    s += __shfl_xor(s, 4, 64);
    float mu = s * (1.f / 128.f);
    float q = 0.f;
#pragma unroll
    for (int m = 0; m < 16; ++m) { acc[m] -= mu; q += acc[m] * acc[m]; }  // d, in place
    q += __shfl_xor(q, 1, 64);
    q += __shfl_xor(q, 2, 64);
    q += __shfl_xor(q, 4, 64);
    float rstd = rsqrtf(q * (1.f / 128.f) + 1e-5f);

    if (g == 0) {
        const float4* g4 = (const float4*)(gamma + f * 16);
        const float4* b4 = (const float4*)(beta + f * 16);
        float4 G0 = g4[0], G1 = g4[1], G2 = g4[2], G3 = g4[3];
        float4 B0 = b4[0], B1 = b4[1], B2 = b4[2], B3 = b4[3];
        bf16x8 o0, o1;
        o0[0] = (__bf16)(acc[ 0] * rstd * G0.x + B0.x);
        o0[1] = (__bf16)(acc[ 1] * rstd * G0.y + B0.y);
        o0[2] = (__bf16)(acc[ 2] * rstd * G0.z + B0.z);
        o0[3] = (__bf16)(acc[ 3] * rstd * G0.w + B0.w);
        o0[4] = (__bf16)(acc[ 4] * rstd * G1.x + B1.x);
        o0[5] = (__bf16)(acc[ 5] * rstd * G1.y + B1.y);
        o0[6] = (__bf16)(acc[ 6] * rstd * G1.z + B1.z);
        o0[7] = (__bf16)(acc[ 7] * rstd * G1.w + B1.w);
        o1[0] = (__bf16)(acc[ 8] * rstd * G2.x + B2.x);
        o1[1] = (__bf16)(acc[ 9] * rstd * G2.y + B2.y);
        o1[2] = (__bf16)(acc[10] * rstd * G2.z + B2.z);
        o1[3] = (__bf16)(acc[11] * rstd * G2.w + B2.w);
        o1[4] = (__bf16)(acc[12] * rstd * G3.x + B3.x);
        o1[5] = (__bf16)(acc[13] * rstd * G3.y + B3.y);
        o1[6] = (__bf16)(acc[14] * rstd * G3.z + B3.z);
        o1[7] = (__bf16)(acc[15] * rstd * G3.w + B3.w);
        *(bf16x8*)(hout + (size_t)node * 128 + f * 16) = o0;
        *(bf16x8*)(hout + (size_t)node * 128 + f * 16 + 8) = o1;
    }
}

// Aggregation 64f (final): 4 lanes x uint4 per edge -> 16 edges per gather
// instruction, 4 divergent addresses per edge. Reduce over g = 4 levels.
// mean + z(fp32) -> out fp32.
__global__ __launch_bounds__(256) void agg_out64(
    const int* __restrict__ offs, const int* __restrict__ ssrc,
    const unsigned char* __restrict__ ybuf,   // [N][64] u8
    const float* __restrict__ yscale,         // [N]
    const float* __restrict__ zbuf,           // [N][64]
    float* __restrict__ out, int nNodes) {
    const int lane = threadIdx.x & 63;
    const int g = lane >> 2;          // edge slot 0..15
    const int f = lane & 3;           // feature 16-tuple 0..3
    const int node = blockIdx.x * 4 + (threadIdx.x >> 6);
    if (node >= nNodes) return;
    const int beg = offs[node], end = offs[node + 1];
    const int deg = end - beg;

    float acc[16] = {};
    float sS = 0.f;
    const int iters = (deg + 15) >> 4;           // 16 edges / iter
    int e = beg + g;
    int idx = 0;
    if (iters > 0) idx = ssrc[(e < end) ? e : beg];
    for (int u = 0; u < iters; ++u) {
        const bool v = e < end;
        uint4 w;
        if (v) w = *(const uint4*)(ybuf + (((unsigned)idx) << 6) + (f << 4));
        float s = yscale[idx];
        int e2 = e + 16;
        int idx2 = ssrc[(e2 < end) ? e2 : beg];
        if (v) { u8_acc16(w, s, acc); sS += s; }
        e = e2; idx = idx2;
    }

    sS += __shfl_xor(sS, 4, 64);
    sS += __shfl_xor(sS, 8, 64);
    sS += __shfl_xor(sS, 16, 64);
    sS += __shfl_xor(sS, 32, 64);
#pragma unroll
    for (int m = 0; m < 16; ++m) {
        acc[m] += __shfl_xor(acc[m], 4, 64);
        acc[m] += __shfl_xor(acc[m], 8, 64);
        acc[m] += __shfl_xor(acc[m], 16, 64);
        acc[m] += __shfl_xor(acc[m], 32, 64);
    }
    if (g == 0) {
        const float inv = 1.f / (float)((deg > 1) ? deg : 1);
        const float bias128 = 128.f * sS;
        const float4* z4 = (const float4*)(zbuf + (size_t)node * 64 + f * 16);
        float4* op = (float4*)(out + (size_t)node * 64 + f * 16);
#pragma unroll
        for (int k = 0; k < 4; ++k) {
            float4 z = z4[k];
            float4 o;
            o.x = (acc[k * 4 + 0] - bias128) * inv + z.x;
            o.y = (acc[k * 4 + 1] - bias128) * inv + z.y;
            o.z = (acc[k * 4 + 2] - bias128) * inv + z.z;
            o.w = (acc[k * 4 + 3] - bias128) * inv + z.w;
            op[k] = o;
        }
    }
}

// ---------------------------------------------------------------------------
extern "C" void kernel_launch(void* const* d_in, const int* in_sizes, int n_in,
                              void* d_out, int out_size, void* d_ws, size_t ws_size,
                              hipStream_t stream) {
    const float* x   = (const float*)d_in[0];
    const int*   ei  = (const int*)d_in[1];
    const float* Wl0 = (const float*)d_in[2];
    const float* Wr0 = (const float*)d_in[3];
    const float* b0  = (const float*)d_in[4];
    const float* Wl1 = (const float*)d_in[5];
    const float* Wr1 = (const float*)d_in[6];
    const float* b1  = (const float*)d_in[7];
    const float* Wl2 = (const float*)d_in[8];
    const float* Wr2 = (const float*)d_in[9];
    const float* b2  = (const float*)d_in[10];
    const float* g0  = (const float*)d_in[11];
    const float* be0 = (const float*)d_in[12];
    const float* g1  = (const float*)d_in[13];
    const float* be1 = (const float*)d_in[14];

    const int N = in_sizes[0] / 128;
    const int E = in_sizes[1] / 2;
    const int* src = ei;
    const int* dst = ei + E;
    float* out = (float*)d_out;

    char* p = (char*)d_ws;
    auto carve = [&](size_t bytes) {
        void* q = (void*)p;
        p += (bytes + 255) & ~(size_t)255;
        return q;
    };
    int*     offs   = (int*)carve(sizeof(int) * (size_t)(N + 1));
    int*     bhist  = (int*)carve(sizeof(int) * (size_t)PB_NB);
    int*     bbase  = (int*)carve(sizeof(int) * (size_t)PB_NB);
    int*     bcur   = (int*)carve(sizeof(int) * (size_t)PB_NB);
    int*     ssrc   = (int*)carve(sizeof(int) * (size_t)E);
    int2*    part   = (int2*)carve(sizeof(int2) * (size_t)E);
    __bf16*  h      = (__bf16*)carve(sizeof(__bf16) * (size_t)N * 128);
    unsigned char* ybuf = (unsigned char*)carve(sizeof(unsigned char) * (size_t)N * 128);
    float*   yscale = (float*)carve(sizeof(float) * (size_t)N);
    void*    zraw   = carve(sizeof(__bf16) * (size_t)N * 128);  // aliased
    __bf16*  zb     = (__bf16*)zraw;   // LN layers: [N][128] bf16
    float*   zf     = (float*)zraw;    // final layer: [N][64] fp32

    // --- CSR build ---
    (void)hipMemsetAsync(bhist, 0, sizeof(int) * PB_NB, stream);
    const int gridE = (E + PB_CHUNK - 1) / PB_CHUNK;
    coarse_hist<<<gridE, PB_BLOCK, 0, stream>>>(dst, bhist, E);
    coarse_scan<<<1, PB_NB, 0, stream>>>(bhist, bbase, bcur);
    part_scatter<<<gridE, PB_BLOCK, 0, stream>>>(src, dst, bcur, part, E);
    bucket_build<<<PB_NB, 256, 0, stream>>>(part, bbase, offs, ssrc, N, E);

    const int gridM = (N + 63) / 64;
    const int gridNode = (N + 3) / 4;

    // --- Layer 0 (A fp32, converted in staging) ---
    gemm_mfma<128, float, __bf16><<<dim3(gridM, 2), 256, 0, stream>>>(x, Wl0, Wr0, b0, ybuf, yscale, zb, N);
    agg_ln128<<<gridNode, 256, 0, stream>>>(offs, ssrc, ybuf, yscale, zb, g0, be0, h, N);
    // --- Layer 1 ---
    gemm_mfma<128, __bf16, __bf16><<<dim3(gridM, 2), 256, 0, stream>>>(h, Wl1, Wr1, b1, ybuf, yscale, zb, N);
    agg_ln128<<<gridNode, 256, 0, stream>>>(offs, ssrc, ybuf, yscale, zb, g1, be1, h, N);
    // --- Layer 2 (64 feats, z fp32, no LN/ReLU) ---
    gemm_mfma<64, __bf16, float><<<dim3(gridM, 2), 256, 0, stream>>>(h, Wl2, Wr2, b2, ybuf, yscale, zf, N);
    agg_out64<<<gridNode, 256, 0, stream>>>(offs, ssrc, ybuf, yscale, zf, out, N);
}

// Round 6
// 438.871 us; speedup vs baseline: 1.0736x; 1.0736x over previous
//
#include <hip/hip_runtime.h>

// ---------------------------------------------------------------------------
// GraphSAGE 3-layer forward, MI355X.
//   CSR build: coarse 256-bucket histogram -> tiny scan -> part_scatter
//     (bucket-grouped int2 edges, dense writes) -> bucket_build (per-bucket
//     LDS count/scan/scatter -> offs + ssrc). No node-level global atomics.
//   Per layer: bf16 MFMA GEMM [y|z] = A @ [Wl;Wr].T (fp32 accum), 64x128
//     tiles; y stored FP16; z bf16 (LN layers) / fp32 (final).
//   Aggregation: R7/R8/R11/R12 showed dur pinned ~69us across byte/address
//     variants with VALUBusy ~75% => VALU-ISSUE bound on per-feature decode
//     (~3 ops/feat for bf16-unpack / int8-cvt+fma alike). Fix: FP16 ybuf +
//     packed v_pk_add_f16 accumulation (0.5 instr/feat, no unpack, no
//     scale). Per-edge decode VALU 48 -> 4 instructions.
// R12->R13: ybuf fp16 + packed-f16 accumulate; yscale deleted; GEMM epilogue
//     reverted to simple store; agg_out64 back to 16-lane-quad shape.
// ---------------------------------------------------------------------------

typedef __bf16    bf16x8 __attribute__((ext_vector_type(8)));
typedef __bf16    bf16x4 __attribute__((ext_vector_type(4)));
typedef float     f32x4  __attribute__((ext_vector_type(4)));
typedef _Float16  f16x2  __attribute__((ext_vector_type(2)));

#define PB_SHIFT 9                      // 512 nodes per coarse bucket
#define PB_NB    256                    // covers N <= 131072
#define PB_EPT   8
#define PB_BLOCK 256
#define PB_CHUNK (PB_BLOCK * PB_EPT)    // 2048 edges per block

__global__ __launch_bounds__(PB_BLOCK) void coarse_hist(
    const int* __restrict__ dst, int* __restrict__ bhist, int E) {
    __shared__ int h[PB_NB];
    const int t = threadIdx.x;
    h[t] = 0;
    __syncthreads();
    const int e0 = blockIdx.x * PB_CHUNK + t;
#pragma unroll
    for (int i = 0; i < PB_EPT; ++i) {
        int e = e0 + i * PB_BLOCK;
        if (e < E) atomicAdd(&h[dst[e] >> PB_SHIFT], 1);
    }
    __syncthreads();
    if (h[t]) atomicAdd(&bhist[t], h[t]);
}

__global__ __launch_bounds__(PB_NB) void coarse_scan(
    const int* __restrict__ bhist, int* __restrict__ bbase, int* __restrict__ bcur) {
    __shared__ int sm[PB_NB];
    const int t = threadIdx.x;
    int v = bhist[t];
    sm[t] = v;
    __syncthreads();
    for (int off = 1; off < PB_NB; off <<= 1) {
        int add = (t >= off) ? sm[t - off] : 0;
        __syncthreads();
        sm[t] += add;
        __syncthreads();
    }
    int excl = sm[t] - v;
    bbase[t] = excl;
    bcur[t] = excl;
}

__global__ __launch_bounds__(PB_BLOCK) void part_scatter(
    const int* __restrict__ src, const int* __restrict__ dst,
    int* __restrict__ bcursor, int2* __restrict__ part, int E) {
    __shared__ int hist[PB_NB];
    __shared__ int base[PB_NB];
    const int t = threadIdx.x;
    hist[t] = 0;
    __syncthreads();
    const int e0 = blockIdx.x * PB_CHUNK + t;
    int my_s[PB_EPT], my_d[PB_EPT], my_r[PB_EPT];
#pragma unroll
    for (int i = 0; i < PB_EPT; ++i) {
        int e = e0 + i * PB_BLOCK;
        if (e < E) {
            my_s[i] = src[e];
            my_d[i] = dst[e];
            my_r[i] = atomicAdd(&hist[my_d[i] >> PB_SHIFT], 1);
        }
    }
    __syncthreads();
    {
        int c = hist[t];
        base[t] = c ? atomicAdd(&bcursor[t], c) : 0;
    }
    __syncthreads();
#pragma unroll
    for (int i = 0; i < PB_EPT; ++i) {
        int e = e0 + i * PB_BLOCK;
        if (e < E) {
            int b = my_d[i] >> PB_SHIFT;
            part[base[b] + my_r[i]] = make_int2(my_s[i], my_d[i]);
        }
    }
}

__global__ __launch_bounds__(256) void bucket_build(
    const int2* __restrict__ part, const int* __restrict__ bbase,
    int* __restrict__ offs, int* __restrict__ ssrc, int N, int E) {
    __shared__ int h[512];
    __shared__ int s[512];
    __shared__ int cur[512];
    const int b = blockIdx.x;
    const int t = threadIdx.x;
    const int beg = bbase[b];
    const int end = (b == PB_NB - 1) ? E : bbase[b + 1];

    h[t] = 0; h[t + 256] = 0;
    __syncthreads();
    for (int e = beg + t; e < end; e += 256)
        atomicAdd(&h[part[e].y & 511], 1);
    __syncthreads();
    s[t] = h[t]; s[t + 256] = h[t + 256];
    __syncthreads();
    for (int off = 1; off < 512; off <<= 1) {
        int a0 = (t >= off) ? s[t - off] : 0;
        int i1 = t + 256;
        int a1 = (i1 >= off) ? s[i1 - off] : 0;
        __syncthreads();
        s[t] += a0; s[i1] += a1;
        __syncthreads();
    }
#pragma unroll
    for (int k = 0; k < 2; ++k) {
        int i = t + k * 256;
        int excl = s[i] - h[i];
        cur[i] = excl;
        int node = (b << PB_SHIFT) + i;
        if (node < N) offs[node] = beg + excl;
    }
    if (b == 0 && t == 0) offs[N] = E;
    __syncthreads();
    for (int e = beg + t; e < end; e += 256) {
        int2 sd = part[e];
        int p = atomicAdd(&cur[sd.y & 511], 1);
        ssrc[beg + p] = sd.x;
    }
}

// ---------------------------------------------------------------------------
// MFMA GEMM: out cols = full DOUT of Wl (by=0 -> ybuf fp16) or Wr (by=1 ->
// zbuf + bias). 64 rows x DOUT cols per block, 4 waves each 32 x DOUT/2.
// K=128 LDS-resident (stride 136 bf16 -> 2-way aliasing, free).
// ---------------------------------------------------------------------------
template <int DOUT, typename AT, typename ZT>
__global__ __launch_bounds__(256) void gemm_mfma(
    const AT* __restrict__ A,
    const float* __restrict__ Wl,
    const float* __restrict__ Wr,
    const float* __restrict__ bias,
    _Float16* __restrict__ ybuf,
    ZT*       __restrict__ zbuf,
    int M) {
    __shared__ __bf16 Asm[64 * 136];
    __shared__ __bf16 Bsm[DOUT * 136];

    const int t = threadIdx.x;
    const int rowBase = blockIdx.x * 64;
    const bool isZ = blockIdx.y != 0;
    const float* W = isZ ? Wr : Wl;

    if constexpr (sizeof(AT) == 4) {
#pragma unroll
        for (int i = 0; i < 8; ++i) {
            int idx = t + 256 * i;
            int r = idx >> 5;
            int c4 = idx & 31;
            int grow = rowBase + r;
            if (grow >= M) grow = M - 1;
            float4 v = *(const float4*)((const float*)A + (size_t)grow * 128 + c4 * 4);
            bf16x4 o;
            o[0] = (__bf16)v.x; o[1] = (__bf16)v.y; o[2] = (__bf16)v.z; o[3] = (__bf16)v.w;
            *(bf16x4*)(Asm + r * 136 + c4 * 4) = o;
        }
    } else {
#pragma unroll
        for (int i = 0; i < 4; ++i) {
            int idx = t + 256 * i;
            int r = idx >> 4;
            int c8 = idx & 15;
            int grow = rowBase + r;
            if (grow >= M) grow = M - 1;
            bf16x8 v = *(const bf16x8*)((const __bf16*)A + (size_t)grow * 128 + c8 * 8);
            *(bf16x8*)(Asm + r * 136 + c8 * 8) = v;
        }
    }
    constexpr int BCH = DOUT * 32 / 256;   // float4 chunks per thread
#pragma unroll
    for (int i = 0; i < BCH; ++i) {
        int idx = t + 256 * i;
        int r = idx >> 5;
        int c4 = idx & 31;
        float4 v = *(const float4*)(W + (size_t)r * 128 + c4 * 4);
        bf16x4 o;
        o[0] = (__bf16)v.x; o[1] = (__bf16)v.y; o[2] = (__bf16)v.z; o[3] = (__bf16)v.w;
        *(bf16x4*)(Bsm + r * 136 + c4 * 4) = o;
    }
    __syncthreads();

    const int lane = t & 63;
    const int wid = t >> 6;
    const int mb = (wid >> 1) * 32;              // row half
    const int nbase = (wid & 1) * (DOUT / 2);    // col half
    constexpr int NJ = DOUT / 32;                // 16-col tiles per wave
    const int ln = lane & 15;
    const int qk = lane >> 4;

    f32x4 acc[2][NJ] = {};
#pragma unroll
    for (int ks = 0; ks < 4; ++ks) {
        const int k0 = ks * 32 + qk * 8;
        bf16x8 a0 = *(const bf16x8*)(Asm + (mb + ln) * 136 + k0);
        bf16x8 a1 = *(const bf16x8*)(Asm + (mb + 16 + ln) * 136 + k0);
        bf16x8 b[NJ];
#pragma unroll
        for (int j = 0; j < NJ; ++j)
            b[j] = *(const bf16x8*)(Bsm + (nbase + j * 16 + ln) * 136 + k0);
#pragma unroll
        for (int j = 0; j < NJ; ++j) {
            acc[0][j] = __builtin_amdgcn_mfma_f32_16x16x32_bf16(a0, b[j], acc[0][j], 0, 0, 0);
            acc[1][j] = __builtin_amdgcn_mfma_f32_16x16x32_bf16(a1, b[j], acc[1][j], 0, 0, 0);
        }
    }

    float bcol[NJ];
    if (isZ) {
#pragma unroll
        for (int j = 0; j < NJ; ++j) bcol[j] = bias[nbase + j * 16 + ln];
    }
    // C/D: col = lane&15, row = (lane>>4)*4 + reg  [m89-verified]
#pragma unroll
    for (int i = 0; i < 2; ++i) {
#pragma unroll
        for (int r = 0; r < 4; ++r) {
            int grow = rowBase + mb + i * 16 + qk * 4 + r;
            if (grow >= M) continue;
#pragma unroll
            for (int j = 0; j < NJ; ++j) {
                int col = nbase + j * 16 + ln;
                float v = acc[i][j][r];
                if (isZ) zbuf[(size_t)grow * DOUT + col] = (ZT)(v + bcol[j]);
                else     ybuf[(size_t)grow * DOUT + col] = (_Float16)v;
            }
        }
    }
}

// ---------------------------------------------------------------------------
// Aggregation 128f: one wave per node; 16-lane quads each handle TWO edges
// per iter (stride 8); fp16 rows (256B), 8 f16/lane via uint4; accumulate
// with packed f16 adds (v_pk_add_f16) -- no unpack, no scale.
// mean + z(bf16) -> ReLU -> LN -> h (bf16).
// ---------------------------------------------------------------------------
__global__ __launch_bounds__(256) void agg_ln128(
    const int* __restrict__ offs, const int* __restrict__ ssrc,
    const _Float16* __restrict__ ybuf,        // [N][128] f16
    const __bf16* __restrict__ zbuf,          // [N][128] bf16
    const float* __restrict__ gamma, const float* __restrict__ beta,
    __bf16* __restrict__ hout, int nNodes) {
    const int lane = threadIdx.x & 63;
    const int qh = lane >> 4;
    const int li = lane & 15;
    const int node = blockIdx.x * 4 + (threadIdx.x >> 6);
    if (node >= nNodes) return;
    const int beg = offs[node], end = offs[node + 1];
    const int deg = end - beg;

    f16x2 pacc[4] = {};
    const int iters = (deg + 7) >> 3;            // 2 edges / quad / iter
    int eA = beg + qh;
    int eB = eA + 4;
    int idxA = 0, idxB = 0;
    if (iters > 0) {
        idxA = ssrc[(eA < end) ? eA : beg];
        idxB = ssrc[(eB < end) ? eB : beg];
    }
    for (int u = 0; u < iters; ++u) {
        const bool va = eA < end;
        const bool vb = eB < end;
        uint4 wa, wb;
        if (va) wa = *(const uint4*)(ybuf + (size_t)idxA * 128 + li * 8);
        if (vb) wb = *(const uint4*)(ybuf + (size_t)idxB * 128 + li * 8);
        int eA2 = eA + 8, eB2 = eB + 8;
        int idxA2 = ssrc[(eA2 < end) ? eA2 : beg];   // prefetch next pair
        int idxB2 = ssrc[(eB2 < end) ? eB2 : beg];
        if (va) {
            pacc[0] += *(const f16x2*)&wa.x;
            pacc[1] += *(const f16x2*)&wa.y;
            pacc[2] += *(const f16x2*)&wa.z;
            pacc[3] += *(const f16x2*)&wa.w;
        }
        if (vb) {
            pacc[0] += *(const f16x2*)&wb.x;
            pacc[1] += *(const f16x2*)&wb.y;
            pacc[2] += *(const f16x2*)&wb.z;
            pacc[3] += *(const f16x2*)&wb.w;
        }
        eA = eA2; eB = eB2; idxA = idxA2; idxB = idxB2;
    }

    // epilogue loads issued before the shuffle chains to overlap latency
    bf16x8 zv = *(const bf16x8*)(zbuf + (size_t)node * 128 + li * 8);
    const float4* g4 = (const float4*)(gamma + li * 8);
    const float4* b4 = (const float4*)(beta + li * 8);
    float4 g0 = g4[0], g1 = g4[1], bb0 = b4[0], bb1 = b4[1];

    // cross-quad reduce on packed regs (2 levels x 4 regs)
#pragma unroll
    for (int m = 0; m < 4; ++m) {
        int w = *(const int*)&pacc[m];
        int w1 = __shfl_xor(w, 16, 64);
        pacc[m] += *(const f16x2*)&w1;
        w = *(const int*)&pacc[m];
        int w2 = __shfl_xor(w, 32, 64);
        pacc[m] += *(const f16x2*)&w2;
    }
    float acc[8];
#pragma unroll
    for (int m = 0; m < 4; ++m) {
        acc[2 * m]     = (float)pacc[m][0];
        acc[2 * m + 1] = (float)pacc[m][1];
    }
    float inv = 1.f / (float)((deg > 1) ? deg : 1);
    float v[8];
#pragma unroll
    for (int m = 0; m < 8; ++m) v[m] = fmaxf(acc[m] * inv + (float)zv[m], 0.f);

    float s = 0.f;
#pragma unroll
    for (int m = 0; m < 8; ++m) s += v[m];
#pragma unroll
    for (int off = 8; off >= 1; off >>= 1) s += __shfl_xor(s, off, 64);
    float mu = s * (1.f / 128.f);
    float d[8], q = 0.f;
#pragma unroll
    for (int m = 0; m < 8; ++m) { d[m] = v[m] - mu; q += d[m] * d[m]; }
#pragma unroll
    for (int off = 8; off >= 1; off >>= 1) q += __shfl_xor(q, off, 64);
    float rstd = rsqrtf(q * (1.f / 128.f) + 1e-5f);

    if (qh == 0) {
        bf16x8 o;
        o[0] = (__bf16)(d[0] * rstd * g0.x + bb0.x);
        o[1] = (__bf16)(d[1] * rstd * g0.y + bb0.y);
        o[2] = (__bf16)(d[2] * rstd * g0.z + bb0.z);
        o[3] = (__bf16)(d[3] * rstd * g0.w + bb0.w);
        o[4] = (__bf16)(d[4] * rstd * g1.x + bb1.x);
        o[5] = (__bf16)(d[5] * rstd * g1.y + bb1.y);
        o[6] = (__bf16)(d[6] * rstd * g1.z + bb1.z);
        o[7] = (__bf16)(d[7] * rstd * g1.w + bb1.w);
        *(bf16x8*)(hout + (size_t)node * 128 + li * 8) = o;
    }
}

// Aggregation 64f (final): 16-lane quads, TWO edges per iter; fp16 rows
// (128B), 4 f16/lane via uint2; packed f16 accumulate; mean + z(fp32) -> f32.
__global__ __launch_bounds__(256) void agg_out64(
    const int* __restrict__ offs, const int* __restrict__ ssrc,
    const _Float16* __restrict__ ybuf,        // [N][64] f16
    const float* __restrict__ zbuf,           // [N][64]
    float* __restrict__ out, int nNodes) {
    const int lane = threadIdx.x & 63;
    const int qh = lane >> 4;
    const int li = lane & 15;
    const int node = blockIdx.x * 4 + (threadIdx.x >> 6);
    if (node >= nNodes) return;
    const int beg = offs[node], end = offs[node + 1];
    const int deg = end - beg;

    f16x2 pacc[2] = {};
    const int iters = (deg + 7) >> 3;            // 2 edges / quad / iter
    int eA = beg + qh;
    int eB = eA + 4;
    int idxA = 0, idxB = 0;
    if (iters > 0) {
        idxA = ssrc[(eA < end) ? eA : beg];
        idxB = ssrc[(eB < end) ? eB : beg];
    }
    for (int u = 0; u < iters; ++u) {
        const bool va = eA < end;
        const bool vb = eB < end;
        uint2 wa, wb;
        if (va) wa = *(const uint2*)(ybuf + (size_t)idxA * 64 + li * 4);
        if (vb) wb = *(const uint2*)(ybuf + (size_t)idxB * 64 + li * 4);
        int eA2 = eA + 8, eB2 = eB + 8;
        int idxA2 = ssrc[(eA2 < end) ? eA2 : beg];
        int idxB2 = ssrc[(eB2 < end) ? eB2 : beg];
        if (va) {
            pacc[0] += *(const f16x2*)&wa.x;
            pacc[1] += *(const f16x2*)&wa.y;
        }
        if (vb) {
            pacc[0] += *(const f16x2*)&wb.x;
            pacc[1] += *(const f16x2*)&wb.y;
        }
        eA = eA2; eB = eB2; idxA = idxA2; idxB = idxB2;
    }

    const float4* z4 = (const float4*)(zbuf + (size_t)node * 64 + li * 4);
    float4 z0 = z4[0];

#pragma unroll
    for (int m = 0; m < 2; ++m) {
        int w = *(const int*)&pacc[m];
        int w1 = __shfl_xor(w, 16, 64);
        pacc[m] += *(const f16x2*)&w1;
        w = *(const int*)&pacc[m];
        int w2 = __shfl_xor(w, 32, 64);
        pacc[m] += *(const f16x2*)&w2;
    }
    if (qh == 0) {
        float inv = 1.f / (float)((deg > 1) ? deg : 1);
        float4 o;
        o.x = (float)pacc[0][0] * inv + z0.x;
        o.y = (float)pacc[0][1] * inv + z0.y;
        o.z = (float)pacc[1][0] * inv + z0.z;
        o.w = (float)pacc[1][1] * inv + z0.w;
        *(float4*)(out + (size_t)node * 64 + li * 4) = o;
    }
}

// ---------------------------------------------------------------------------
extern "C" void kernel_launch(void* const* d_in, const int* in_sizes, int n_in,
                              void* d_out, int out_size, void* d_ws, size_t ws_size,
                              hipStream_t stream) {
    const float* x   = (const float*)d_in[0];
    const int*   ei  = (const int*)d_in[1];
    const float* Wl0 = (const float*)d_in[2];
    const float* Wr0 = (const float*)d_in[3];
    const float* b0  = (const float*)d_in[4];
    const float* Wl1 = (const float*)d_in[5];
    const float* Wr1 = (const float*)d_in[6];
    const float* b1  = (const float*)d_in[7];
    const float* Wl2 = (const float*)d_in[8];
    const float* Wr2 = (const float*)d_in[9];
    const float* b2  = (const float*)d_in[10];
    const float* g0  = (const float*)d_in[11];
    const float* be0 = (const float*)d_in[12];
    const float* g1  = (const float*)d_in[13];
    const float* be1 = (const float*)d_in[14];

    const int N = in_sizes[0] / 128;
    const int E = in_sizes[1] / 2;
    const int* src = ei;
    const int* dst = ei + E;
    float* out = (float*)d_out;

    char* p = (char*)d_ws;
    auto carve = [&](size_t bytes) {
        void* q = (void*)p;
        p += (bytes + 255) & ~(size_t)255;
        return q;
    };
    int*      offs  = (int*)carve(sizeof(int) * (size_t)(N + 1));
    int*      bhist = (int*)carve(sizeof(int) * (size_t)PB_NB);
    int*      bbase = (int*)carve(sizeof(int) * (size_t)PB_NB);
    int*      bcur  = (int*)carve(sizeof(int) * (size_t)PB_NB);
    int*      ssrc  = (int*)carve(sizeof(int) * (size_t)E);
    int2*     part  = (int2*)carve(sizeof(int2) * (size_t)E);
    __bf16*   h     = (__bf16*)carve(sizeof(__bf16) * (size_t)N * 128);
    _Float16* ybuf  = (_Float16*)carve(sizeof(_Float16) * (size_t)N * 128);
    void*     zraw  = carve(sizeof(__bf16) * (size_t)N * 128);  // aliased
    __bf16*   zb    = (__bf16*)zraw;   // LN layers: [N][128] bf16
    float*    zf    = (float*)zraw;    // final layer: [N][64] fp32

    // --- CSR build ---
    (void)hipMemsetAsync(bhist, 0, sizeof(int) * PB_NB, stream);
    const int gridE = (E + PB_CHUNK - 1) / PB_CHUNK;
    coarse_hist<<<gridE, PB_BLOCK, 0, stream>>>(dst, bhist, E);
    coarse_scan<<<1, PB_NB, 0, stream>>>(bhist, bbase, bcur);
    part_scatter<<<gridE, PB_BLOCK, 0, stream>>>(src, dst, bcur, part, E);
    bucket_build<<<PB_NB, 256, 0, stream>>>(part, bbase, offs, ssrc, N, E);

    const int gridM = (N + 63) / 64;
    const int gridNode = (N + 3) / 4;

    // --- Layer 0 (A fp32, converted in staging) ---
    gemm_mfma<128, float, __bf16><<<dim3(gridM, 2), 256, 0, stream>>>(x, Wl0, Wr0, b0, ybuf, zb, N);
    agg_ln128<<<gridNode, 256, 0, stream>>>(offs, ssrc, ybuf, zb, g0, be0, h, N);
    // --- Layer 1 ---
    gemm_mfma<128, __bf16, __bf16><<<dim3(gridM, 2), 256, 0, stream>>>(h, Wl1, Wr1, b1, ybuf, zb, N);
    agg_ln128<<<gridNode, 256, 0, stream>>>(offs, ssrc, ybuf, zb, g1, be1, h, N);
    // --- Layer 2 (64 feats, z fp32, no LN/ReLU) ---
    gemm_mfma<64, __bf16, float><<<dim3(gridM, 2), 256, 0, stream>>>(h, Wl2, Wr2, b2, ybuf, zf, N);
    agg_out64<<<gridNode, 256, 0, stream>>>(offs, ssrc, ybuf, zf, out, N);
}

// Round 7
// 427.877 us; speedup vs baseline: 1.1012x; 1.0257x over previous
//
#include <hip/hip_runtime.h>

// ---------------------------------------------------------------------------
// GraphSAGE 3-layer forward, MI355X.
//   CSR build: coarse 256-bucket histogram -> tiny scan -> part_scatter
//     (bucket-grouped int2 edges, dense writes) -> bucket_build (per-bucket
//     LDS count/scan/scatter -> offs + ssrc). No node-level global atomics.
//   Per layer: bf16 MFMA GEMM, ONE block per 64-row tile computes BOTH
//     y (Wl) and z (Wr) phases -- A staged ONCE (R13 staged it twice via
//     blockIdx.y), Wl/Wr staged sequentially into the same LDS buffer.
//   Aggregation: AT STRUCTURAL FLOOR (~70us/dispatch): across
//     bf16/int8/fp16 x 1-2 deep x 4-16 rows/instr, duration pinned 69-71us
//     => ~1 random L2 request per edge at ~1.2 req/cyc/XCD is binding.
//     fp16 ybuf + packed v_pk_add_f16 accumulate (lowest VALU variant kept).
// R13->R14: gemm y/z fused (A-traffic halved, blocks halved); agg unchanged.
// ---------------------------------------------------------------------------

typedef __bf16    bf16x8 __attribute__((ext_vector_type(8)));
typedef __bf16    bf16x4 __attribute__((ext_vector_type(4)));
typedef float     f32x4  __attribute__((ext_vector_type(4)));
typedef _Float16  f16x2  __attribute__((ext_vector_type(2)));

#define PB_SHIFT 9                      // 512 nodes per coarse bucket
#define PB_NB    256                    // covers N <= 131072
#define PB_EPT   8
#define PB_BLOCK 256
#define PB_CHUNK (PB_BLOCK * PB_EPT)    // 2048 edges per block

__global__ __launch_bounds__(PB_BLOCK) void coarse_hist(
    const int* __restrict__ dst, int* __restrict__ bhist, int E) {
    __shared__ int h[PB_NB];
    const int t = threadIdx.x;
    h[t] = 0;
    __syncthreads();
    const int e0 = blockIdx.x * PB_CHUNK + t;
#pragma unroll
    for (int i = 0; i < PB_EPT; ++i) {
        int e = e0 + i * PB_BLOCK;
        if (e < E) atomicAdd(&h[dst[e] >> PB_SHIFT], 1);
    }
    __syncthreads();
    if (h[t]) atomicAdd(&bhist[t], h[t]);
}

__global__ __launch_bounds__(PB_NB) void coarse_scan(
    const int* __restrict__ bhist, int* __restrict__ bbase, int* __restrict__ bcur) {
    __shared__ int sm[PB_NB];
    const int t = threadIdx.x;
    int v = bhist[t];
    sm[t] = v;
    __syncthreads();
    for (int off = 1; off < PB_NB; off <<= 1) {
        int add = (t >= off) ? sm[t - off] : 0;
        __syncthreads();
        sm[t] += add;
        __syncthreads();
    }
    int excl = sm[t] - v;
    bbase[t] = excl;
    bcur[t] = excl;
}

__global__ __launch_bounds__(PB_BLOCK) void part_scatter(
    const int* __restrict__ src, const int* __restrict__ dst,
    int* __restrict__ bcursor, int2* __restrict__ part, int E) {
    __shared__ int hist[PB_NB];
    __shared__ int base[PB_NB];
    const int t = threadIdx.x;
    hist[t] = 0;
    __syncthreads();
    const int e0 = blockIdx.x * PB_CHUNK + t;
    int my_s[PB_EPT], my_d[PB_EPT], my_r[PB_EPT];
#pragma unroll
    for (int i = 0; i < PB_EPT; ++i) {
        int e = e0 + i * PB_BLOCK;
        if (e < E) {
            my_s[i] = src[e];
            my_d[i] = dst[e];
            my_r[i] = atomicAdd(&hist[my_d[i] >> PB_SHIFT], 1);
        }
    }
    __syncthreads();
    {
        int c = hist[t];
        base[t] = c ? atomicAdd(&bcursor[t], c) : 0;
    }
    __syncthreads();
#pragma unroll
    for (int i = 0; i < PB_EPT; ++i) {
        int e = e0 + i * PB_BLOCK;
        if (e < E) {
            int b = my_d[i] >> PB_SHIFT;
            part[base[b] + my_r[i]] = make_int2(my_s[i], my_d[i]);
        }
    }
}

__global__ __launch_bounds__(256) void bucket_build(
    const int2* __restrict__ part, const int* __restrict__ bbase,
    int* __restrict__ offs, int* __restrict__ ssrc, int N, int E) {
    __shared__ int h[512];
    __shared__ int s[512];
    __shared__ int cur[512];
    const int b = blockIdx.x;
    const int t = threadIdx.x;
    const int beg = bbase[b];
    const int end = (b == PB_NB - 1) ? E : bbase[b + 1];

    h[t] = 0; h[t + 256] = 0;
    __syncthreads();
    for (int e = beg + t; e < end; e += 256)
        atomicAdd(&h[part[e].y & 511], 1);
    __syncthreads();
    s[t] = h[t]; s[t + 256] = h[t + 256];
    __syncthreads();
    for (int off = 1; off < 512; off <<= 1) {
        int a0 = (t >= off) ? s[t - off] : 0;
        int i1 = t + 256;
        int a1 = (i1 >= off) ? s[i1 - off] : 0;
        __syncthreads();
        s[t] += a0; s[i1] += a1;
        __syncthreads();
    }
#pragma unroll
    for (int k = 0; k < 2; ++k) {
        int i = t + k * 256;
        int excl = s[i] - h[i];
        cur[i] = excl;
        int node = (b << PB_SHIFT) + i;
        if (node < N) offs[node] = beg + excl;
    }
    if (b == 0 && t == 0) offs[N] = E;
    __syncthreads();
    for (int e = beg + t; e < end; e += 256) {
        int2 sd = part[e];
        int p = atomicAdd(&cur[sd.y & 511], 1);
        ssrc[beg + p] = sd.x;
    }
}

// ---------------------------------------------------------------------------
// Fused MFMA GEMM: one block per 64-row tile. Stage A once; phase 0: Wl in
// LDS -> y (f16); barrier; phase 1: Wr into same LDS -> z (+bias).
// K=128 LDS-resident (stride 136 bf16 -> 2-way aliasing, free).
// ---------------------------------------------------------------------------
template <int DOUT, typename AT, typename ZT>
__global__ __launch_bounds__(256) void gemm_mfma(
    const AT* __restrict__ A,
    const float* __restrict__ Wl,
    const float* __restrict__ Wr,
    const float* __restrict__ bias,
    _Float16* __restrict__ ybuf,
    ZT*       __restrict__ zbuf,
    int M) {
    __shared__ __bf16 Asm[64 * 136];
    __shared__ __bf16 Bsm[DOUT * 136];

    const int t = threadIdx.x;
    const int rowBase = blockIdx.x * 64;

    // ---- stage A (once) ----
    if constexpr (sizeof(AT) == 4) {
#pragma unroll
        for (int i = 0; i < 8; ++i) {
            int idx = t + 256 * i;
            int r = idx >> 5;
            int c4 = idx & 31;
            int grow = rowBase + r;
            if (grow >= M) grow = M - 1;
            float4 v = *(const float4*)((const float*)A + (size_t)grow * 128 + c4 * 4);
            bf16x4 o;
            o[0] = (__bf16)v.x; o[1] = (__bf16)v.y; o[2] = (__bf16)v.z; o[3] = (__bf16)v.w;
            *(bf16x4*)(Asm + r * 136 + c4 * 4) = o;
        }
    } else {
#pragma unroll
        for (int i = 0; i < 4; ++i) {
            int idx = t + 256 * i;
            int r = idx >> 4;
            int c8 = idx & 15;
            int grow = rowBase + r;
            if (grow >= M) grow = M - 1;
            bf16x8 v = *(const bf16x8*)((const __bf16*)A + (size_t)grow * 128 + c8 * 8);
            *(bf16x8*)(Asm + r * 136 + c8 * 8) = v;
        }
    }

    const int lane = t & 63;
    const int wid = t >> 6;
    const int mb = (wid >> 1) * 32;              // row half
    const int nbase = (wid & 1) * (DOUT / 2);    // col half
    constexpr int NJ = DOUT / 32;                // 16-col tiles per wave
    const int ln = lane & 15;
    const int qk = lane >> 4;
    constexpr int BCH = DOUT * 32 / 256;         // float4 chunks per thread

#pragma unroll
    for (int phase = 0; phase < 2; ++phase) {
        const bool isZ = phase != 0;
        const float* W = isZ ? Wr : Wl;

        // ---- stage W into Bsm (phase 1 overwrites; Asm persists) ----
#pragma unroll
        for (int i = 0; i < BCH; ++i) {
            int idx = t + 256 * i;
            int r = idx >> 5;
            int c4 = idx & 31;
            float4 v = *(const float4*)(W + (size_t)r * 128 + c4 * 4);
            bf16x4 o;
            o[0] = (__bf16)v.x; o[1] = (__bf16)v.y; o[2] = (__bf16)v.z; o[3] = (__bf16)v.w;
            *(bf16x4*)(Bsm + r * 136 + c4 * 4) = o;
        }
        __syncthreads();

        f32x4 acc[2][NJ] = {};
#pragma unroll
        for (int ks = 0; ks < 4; ++ks) {
            const int k0 = ks * 32 + qk * 8;
            bf16x8 a0 = *(const bf16x8*)(Asm + (mb + ln) * 136 + k0);
            bf16x8 a1 = *(const bf16x8*)(Asm + (mb + 16 + ln) * 136 + k0);
            bf16x8 b[NJ];
#pragma unroll
            for (int j = 0; j < NJ; ++j)
                b[j] = *(const bf16x8*)(Bsm + (nbase + j * 16 + ln) * 136 + k0);
#pragma unroll
            for (int j = 0; j < NJ; ++j) {
                acc[0][j] = __builtin_amdgcn_mfma_f32_16x16x32_bf16(a0, b[j], acc[0][j], 0, 0, 0);
                acc[1][j] = __builtin_amdgcn_mfma_f32_16x16x32_bf16(a1, b[j], acc[1][j], 0, 0, 0);
            }
        }

        float bcol[NJ];
        if (isZ) {
#pragma unroll
            for (int j = 0; j < NJ; ++j) bcol[j] = bias[nbase + j * 16 + ln];
        }
        // C/D: col = lane&15, row = (lane>>4)*4 + reg  [m89-verified]
#pragma unroll
        for (int i = 0; i < 2; ++i) {
#pragma unroll
            for (int r = 0; r < 4; ++r) {
                int grow = rowBase + mb + i * 16 + qk * 4 + r;
                if (grow >= M) continue;
#pragma unroll
                for (int j = 0; j < NJ; ++j) {
                    int col = nbase + j * 16 + ln;
                    float v = acc[i][j][r];
                    if (isZ) zbuf[(size_t)grow * DOUT + col] = (ZT)(v + bcol[j]);
                    else     ybuf[(size_t)grow * DOUT + col] = (_Float16)v;
                }
            }
        }
        __syncthreads();   // all Bsm reads done before next phase's restage
    }
}

// ---------------------------------------------------------------------------
// Aggregation 128f: one wave per node; 16-lane quads each handle TWO edges
// per iter (stride 8); fp16 rows (256B), 8 f16/lane via uint4; accumulate
// with packed f16 adds -- no unpack, no scale.
// mean + z(bf16) -> ReLU -> LN -> h (bf16).
// ---------------------------------------------------------------------------
__global__ __launch_bounds__(256) void agg_ln128(
    const int* __restrict__ offs, const int* __restrict__ ssrc,
    const _Float16* __restrict__ ybuf,        // [N][128] f16
    const __bf16* __restrict__ zbuf,          // [N][128] bf16
    const float* __restrict__ gamma, const float* __restrict__ beta,
    __bf16* __restrict__ hout, int nNodes) {
    const int lane = threadIdx.x & 63;
    const int qh = lane >> 4;
    const int li = lane & 15;
    const int node = blockIdx.x * 4 + (threadIdx.x >> 6);
    if (node >= nNodes) return;
    const int beg = offs[node], end = offs[node + 1];
    const int deg = end - beg;

    f16x2 pacc[4] = {};
    const int iters = (deg + 7) >> 3;            // 2 edges / quad / iter
    int eA = beg + qh;
    int eB = eA + 4;
    int idxA = 0, idxB = 0;
    if (iters > 0) {
        idxA = ssrc[(eA < end) ? eA : beg];
        idxB = ssrc[(eB < end) ? eB : beg];
    }
    for (int u = 0; u < iters; ++u) {
        const bool va = eA < end;
        const bool vb = eB < end;
        uint4 wa, wb;
        if (va) wa = *(const uint4*)(ybuf + (size_t)idxA * 128 + li * 8);
        if (vb) wb = *(const uint4*)(ybuf + (size_t)idxB * 128 + li * 8);
        int eA2 = eA + 8, eB2 = eB + 8;
        int idxA2 = ssrc[(eA2 < end) ? eA2 : beg];   // prefetch next pair
        int idxB2 = ssrc[(eB2 < end) ? eB2 : beg];
        if (va) {
            pacc[0] += *(const f16x2*)&wa.x;
            pacc[1] += *(const f16x2*)&wa.y;
            pacc[2] += *(const f16x2*)&wa.z;
            pacc[3] += *(const f16x2*)&wa.w;
        }
        if (vb) {
            pacc[0] += *(const f16x2*)&wb.x;
            pacc[1] += *(const f16x2*)&wb.y;
            pacc[2] += *(const f16x2*)&wb.z;
            pacc[3] += *(const f16x2*)&wb.w;
        }
        eA = eA2; eB = eB2; idxA = idxA2; idxB = idxB2;
    }

    // epilogue loads issued before the shuffle chains to overlap latency
    bf16x8 zv = *(const bf16x8*)(zbuf + (size_t)node * 128 + li * 8);
    const float4* g4 = (const float4*)(gamma + li * 8);
    const float4* b4 = (const float4*)(beta + li * 8);
    float4 g0 = g4[0], g1 = g4[1], bb0 = b4[0], bb1 = b4[1];

    // cross-quad reduce on packed regs (2 levels x 4 regs)
#pragma unroll
    for (int m = 0; m < 4; ++m) {
        int w = *(const int*)&pacc[m];
        int w1 = __shfl_xor(w, 16, 64);
        pacc[m] += *(const f16x2*)&w1;
        w = *(const int*)&pacc[m];
        int w2 = __shfl_xor(w, 32, 64);
        pacc[m] += *(const f16x2*)&w2;
    }
    float acc[8];
#pragma unroll
    for (int m = 0; m < 4; ++m) {
        acc[2 * m]     = (float)pacc[m][0];
        acc[2 * m + 1] = (float)pacc[m][1];
    }
    float inv = 1.f / (float)((deg > 1) ? deg : 1);
    float v[8];
#pragma unroll
    for (int m = 0; m < 8; ++m) v[m] = fmaxf(acc[m] * inv + (float)zv[m], 0.f);

    float s = 0.f;
#pragma unroll
    for (int m = 0; m < 8; ++m) s += v[m];
#pragma unroll
    for (int off = 8; off >= 1; off >>= 1) s += __shfl_xor(s, off, 64);
    float mu = s * (1.f / 128.f);
    float d[8], q = 0.f;
#pragma unroll
    for (int m = 0; m < 8; ++m) { d[m] = v[m] - mu; q += d[m] * d[m]; }
#pragma unroll
    for (int off = 8; off >= 1; off >>= 1) q += __shfl_xor(q, off, 64);
    float rstd = rsqrtf(q * (1.f / 128.f) + 1e-5f);

    if (qh == 0) {
        bf16x8 o;
        o[0] = (__bf16)(d[0] * rstd * g0.x + bb0.x);
        o[1] = (__bf16)(d[1] * rstd * g0.y + bb0.y);
        o[2] = (__bf16)(d[2] * rstd * g0.z + bb0.z);
        o[3] = (__bf16)(d[3] * rstd * g0.w + bb0.w);
        o[4] = (__bf16)(d[4] * rstd * g1.x + bb1.x);
        o[5] = (__bf16)(d[5] * rstd * g1.y + bb1.y);
        o[6] = (__bf16)(d[6] * rstd * g1.z + bb1.z);
        o[7] = (__bf16)(d[7] * rstd * g1.w + bb1.w);
        *(bf16x8*)(hout + (size_t)node * 128 + li * 8) = o;
    }
}

// Aggregation 64f (final): 16-lane quads, TWO edges per iter; fp16 rows
// (128B), 4 f16/lane via uint2; packed f16 accumulate; mean + z(fp32) -> f32.
__global__ __launch_bounds__(256) void agg_out64(
    const int* __restrict__ offs, const int* __restrict__ ssrc,
    const _Float16* __restrict__ ybuf,        // [N][64] f16
    const float* __restrict__ zbuf,           // [N][64]
    float* __restrict__ out, int nNodes) {
    const int lane = threadIdx.x & 63;
    const int qh = lane >> 4;
    const int li = lane & 15;
    const int node = blockIdx.x * 4 + (threadIdx.x >> 6);
    if (node >= nNodes) return;
    const int beg = offs[node], end = offs[node + 1];
    const int deg = end - beg;

    f16x2 pacc[2] = {};
    const int iters = (deg + 7) >> 3;            // 2 edges / quad / iter
    int eA = beg + qh;
    int eB = eA + 4;
    int idxA = 0, idxB = 0;
    if (iters > 0) {
        idxA = ssrc[(eA < end) ? eA : beg];
        idxB = ssrc[(eB < end) ? eB : beg];
    }
    for (int u = 0; u < iters; ++u) {
        const bool va = eA < end;
        const bool vb = eB < end;
        uint2 wa, wb;
        if (va) wa = *(const uint2*)(ybuf + (size_t)idxA * 64 + li * 4);
        if (vb) wb = *(const uint2*)(ybuf + (size_t)idxB * 64 + li * 4);
        int eA2 = eA + 8, eB2 = eB + 8;
        int idxA2 = ssrc[(eA2 < end) ? eA2 : beg];
        int idxB2 = ssrc[(eB2 < end) ? eB2 : beg];
        if (va) {
            pacc[0] += *(const f16x2*)&wa.x;
            pacc[1] += *(const f16x2*)&wa.y;
        }
        if (vb) {
            pacc[0] += *(const f16x2*)&wb.x;
            pacc[1] += *(const f16x2*)&wb.y;
        }
        eA = eA2; eB = eB2; idxA = idxA2; idxB = idxB2;
    }

    const float4* z4 = (const float4*)(zbuf + (size_t)node * 64 + li * 4);
    float4 z0 = z4[0];

#pragma unroll
    for (int m = 0; m < 2; ++m) {
        int w = *(const int*)&pacc[m];
        int w1 = __shfl_xor(w, 16, 64);
        pacc[m] += *(const f16x2*)&w1;
        w = *(const int*)&pacc[m];
        int w2 = __shfl_xor(w, 32, 64);
        pacc[m] += *(const f16x2*)&w2;
    }
    if (qh == 0) {
        float inv = 1.f / (float)((deg > 1) ? deg : 1);
        float4 o;
        o.x = (float)pacc[0][0] * inv + z0.x;
        o.y = (float)pacc[0][1] * inv + z0.y;
        o.z = (float)pacc[1][0] * inv + z0.z;
        o.w = (float)pacc[1][1] * inv + z0.w;
        *(float4*)(out + (size_t)node * 64 + li * 4) = o;
    }
}

// ---------------------------------------------------------------------------
extern "C" void kernel_launch(void* const* d_in, const int* in_sizes, int n_in,
                              void* d_out, int out_size, void* d_ws, size_t ws_size,
                              hipStream_t stream) {
    const float* x   = (const float*)d_in[0];
    const int*   ei  = (const int*)d_in[1];
    const float* Wl0 = (const float*)d_in[2];
    const float* Wr0 = (const float*)d_in[3];
    const float* b0  = (const float*)d_in[4];
    const float* Wl1 = (const float*)d_in[5];
    const float* Wr1 = (const float*)d_in[6];
    const float* b1  = (const float*)d_in[7];
    const float* Wl2 = (const float*)d_in[8];
    const float* Wr2 = (const float*)d_in[9];
    const float* b2  = (const float*)d_in[10];
    const float* g0  = (const float*)d_in[11];
    const float* be0 = (const float*)d_in[12];
    const float* g1  = (const float*)d_in[13];
    const float* be1 = (const float*)d_in[14];

    const int N = in_sizes[0] / 128;
    const int E = in_sizes[1] / 2;
    const int* src = ei;
    const int* dst = ei + E;
    float* out = (float*)d_out;

    char* p = (char*)d_ws;
    auto carve = [&](size_t bytes) {
        void* q = (void*)p;
        p += (bytes + 255) & ~(size_t)255;
        return q;
    };
    int*      offs  = (int*)carve(sizeof(int) * (size_t)(N + 1));
    int*      bhist = (int*)carve(sizeof(int) * (size_t)PB_NB);
    int*      bbase = (int*)carve(sizeof(int) * (size_t)PB_NB);
    int*      bcur  = (int*)carve(sizeof(int) * (size_t)PB_NB);
    int*      ssrc  = (int*)carve(sizeof(int) * (size_t)E);
    int2*     part  = (int2*)carve(sizeof(int2) * (size_t)E);
    __bf16*   h     = (__bf16*)carve(sizeof(__bf16) * (size_t)N * 128);
    _Float16* ybuf  = (_Float16*)carve(sizeof(_Float16) * (size_t)N * 128);
    void*     zraw  = carve(sizeof(__bf16) * (size_t)N * 128);  // aliased
    __bf16*   zb    = (__bf16*)zraw;   // LN layers: [N][128] bf16
    float*    zf    = (float*)zraw;    // final layer: [N][64] fp32

    // --- CSR build ---
    (void)hipMemsetAsync(bhist, 0, sizeof(int) * PB_NB, stream);
    const int gridE = (E + PB_CHUNK - 1) / PB_CHUNK;
    coarse_hist<<<gridE, PB_BLOCK, 0, stream>>>(dst, bhist, E);
    coarse_scan<<<1, PB_NB, 0, stream>>>(bhist, bbase, bcur);
    part_scatter<<<gridE, PB_BLOCK, 0, stream>>>(src, dst, bcur, part, E);
    bucket_build<<<PB_NB, 256, 0, stream>>>(part, bbase, offs, ssrc, N, E);

    const int gridM = (N + 63) / 64;
    const int gridNode = (N + 3) / 4;

    // --- Layer 0 (A fp32, converted in staging) ---
    gemm_mfma<128, float, __bf16><<<gridM, 256, 0, stream>>>(x, Wl0, Wr0, b0, ybuf, zb, N);
    agg_ln128<<<gridNode, 256, 0, stream>>>(offs, ssrc, ybuf, zb, g0, be0, h, N);
    // --- Layer 1 ---
    gemm_mfma<128, __bf16, __bf16><<<gridM, 256, 0, stream>>>(h, Wl1, Wr1, b1, ybuf, zb, N);
    agg_ln128<<<gridNode, 256, 0, stream>>>(offs, ssrc, ybuf, zb, g1, be1, h, N);
    // --- Layer 2 (64 feats, z fp32, no LN/ReLU) ---
    gemm_mfma<64, __bf16, float><<<gridM, 256, 0, stream>>>(h, Wl2, Wr2, b2, ybuf, zf, N);
    agg_out64<<<gridNode, 256, 0, stream>>>(offs, ssrc, ybuf, zf, out, N);
}

// Round 8
// 423.573 us; speedup vs baseline: 1.1124x; 1.0102x over previous
//
#include <hip/hip_runtime.h>

// ---------------------------------------------------------------------------
// GraphSAGE 3-layer forward, MI355X.
//   CSR build: coarse 256-bucket histogram -> tiny scan -> part_scatter
//     (bucket-grouped int2 edges, dense writes) -> bucket_build (per-bucket
//     LDS count/scan/scatter -> offs + ssrc). No node-level global atomics.
//   Per layer: bf16 MFMA GEMM, 256 PERSISTENT blocks x 512 threads:
//     Wl+Wr staged into LDS ONCE per block (both resident), grid-stride over
//     128-row A-tiles with double-buffered A staging (stage t+1 overlaps
//     MFMA of t, one barrier per tile). y f16; z bf16 (LN) / fp32 (final).
//   Aggregation: AT STRUCTURAL FLOOR (~70us/dispatch): across
//     bf16/int8/fp16 x 1-2 deep x 4-16 rows/instr, duration pinned 69-71us
//     => ~1 random L2-missing request per edge (MSHR x latency) binding.
//     fp16 ybuf + packed v_pk_add_f16 accumulate (lowest VALU variant kept).
// R14->R15: GEMM persistent-W + multi-tile + A double-buffer; agg unchanged.
// ---------------------------------------------------------------------------

typedef __bf16    bf16x8 __attribute__((ext_vector_type(8)));
typedef __bf16    bf16x4 __attribute__((ext_vector_type(4)));
typedef float     f32x4  __attribute__((ext_vector_type(4)));
typedef _Float16  f16x2  __attribute__((ext_vector_type(2)));

#define PB_SHIFT 9                      // 512 nodes per coarse bucket
#define PB_NB    256                    // covers N <= 131072
#define PB_EPT   8
#define PB_BLOCK 256
#define PB_CHUNK (PB_BLOCK * PB_EPT)    // 2048 edges per block

__global__ __launch_bounds__(PB_BLOCK) void coarse_hist(
    const int* __restrict__ dst, int* __restrict__ bhist, int E) {
    __shared__ int h[PB_NB];
    const int t = threadIdx.x;
    h[t] = 0;
    __syncthreads();
    const int e0 = blockIdx.x * PB_CHUNK + t;
#pragma unroll
    for (int i = 0; i < PB_EPT; ++i) {
        int e = e0 + i * PB_BLOCK;
        if (e < E) atomicAdd(&h[dst[e] >> PB_SHIFT], 1);
    }
    __syncthreads();
    if (h[t]) atomicAdd(&bhist[t], h[t]);
}

__global__ __launch_bounds__(PB_NB) void coarse_scan(
    const int* __restrict__ bhist, int* __restrict__ bbase, int* __restrict__ bcur) {
    __shared__ int sm[PB_NB];
    const int t = threadIdx.x;
    int v = bhist[t];
    sm[t] = v;
    __syncthreads();
    for (int off = 1; off < PB_NB; off <<= 1) {
        int add = (t >= off) ? sm[t - off] : 0;
        __syncthreads();
        sm[t] += add;
        __syncthreads();
    }
    int excl = sm[t] - v;
    bbase[t] = excl;
    bcur[t] = excl;
}

__global__ __launch_bounds__(PB_BLOCK) void part_scatter(
    const int* __restrict__ src, const int* __restrict__ dst,
    int* __restrict__ bcursor, int2* __restrict__ part, int E) {
    __shared__ int hist[PB_NB];
    __shared__ int base[PB_NB];
    const int t = threadIdx.x;
    hist[t] = 0;
    __syncthreads();
    const int e0 = blockIdx.x * PB_CHUNK + t;
    int my_s[PB_EPT], my_d[PB_EPT], my_r[PB_EPT];
#pragma unroll
    for (int i = 0; i < PB_EPT; ++i) {
        int e = e0 + i * PB_BLOCK;
        if (e < E) {
            my_s[i] = src[e];
            my_d[i] = dst[e];
            my_r[i] = atomicAdd(&hist[my_d[i] >> PB_SHIFT], 1);
        }
    }
    __syncthreads();
    {
        int c = hist[t];
        base[t] = c ? atomicAdd(&bcursor[t], c) : 0;
    }
    __syncthreads();
#pragma unroll
    for (int i = 0; i < PB_EPT; ++i) {
        int e = e0 + i * PB_BLOCK;
        if (e < E) {
            int b = my_d[i] >> PB_SHIFT;
            part[base[b] + my_r[i]] = make_int2(my_s[i], my_d[i]);
        }
    }
}

__global__ __launch_bounds__(256) void bucket_build(
    const int2* __restrict__ part, const int* __restrict__ bbase,
    int* __restrict__ offs, int* __restrict__ ssrc, int N, int E) {
    __shared__ int h[512];
    __shared__ int s[512];
    __shared__ int cur[512];
    const int b = blockIdx.x;
    const int t = threadIdx.x;
    const int beg = bbase[b];
    const int end = (b == PB_NB - 1) ? E : bbase[b + 1];

    h[t] = 0; h[t + 256] = 0;
    __syncthreads();
    for (int e = beg + t; e < end; e += 256)
        atomicAdd(&h[part[e].y & 511], 1);
    __syncthreads();
    s[t] = h[t]; s[t + 256] = h[t + 256];
    __syncthreads();
    for (int off = 1; off < 512; off <<= 1) {
        int a0 = (t >= off) ? s[t - off] : 0;
        int i1 = t + 256;
        int a1 = (i1 >= off) ? s[i1 - off] : 0;
        __syncthreads();
        s[t] += a0; s[i1] += a1;
        __syncthreads();
    }
#pragma unroll
    for (int k = 0; k < 2; ++k) {
        int i = t + k * 256;
        int excl = s[i] - h[i];
        cur[i] = excl;
        int node = (b << PB_SHIFT) + i;
        if (node < N) offs[node] = beg + excl;
    }
    if (b == 0 && t == 0) offs[N] = E;
    __syncthreads();
    for (int e = beg + t; e < end; e += 256) {
        int2 sd = part[e];
        int p = atomicAdd(&cur[sd.y & 511], 1);
        ssrc[beg + p] = sd.x;
    }
}

// ---------------------------------------------------------------------------
// Persistent-W MFMA GEMM. 512 threads (8 waves), 1 block/CU (LDS ~139KB for
// DOUT=128). Prologue: Wl->Wsm[0], Wr->Wsm[1] (bf16, once). Main loop:
// grid-stride over 128-row tiles; A double-buffered (stage next while
// computing current); per tile compute BOTH y (Wsm[0]) and z (Wsm[1]).
// K=128 LDS-resident (stride 136 bf16 -> 2-way aliasing, free).
// ---------------------------------------------------------------------------
template <int DOUT, typename AT, typename ZT>
__global__ __launch_bounds__(512) void gemm_mfma(
    const AT* __restrict__ A,
    const float* __restrict__ Wl,
    const float* __restrict__ Wr,
    const float* __restrict__ bias,
    _Float16* __restrict__ ybuf,
    ZT*       __restrict__ zbuf,
    int M) {
    __shared__ __bf16 Asm[2][128 * 136];
    __shared__ __bf16 Wsm[2][DOUT * 136];

    const int t = threadIdx.x;
    const int nt = (M + 127) >> 7;               // 128-row tiles

    // ---- stage Wl, Wr once ----
    constexpr int WCH = DOUT * 32 / 512;         // float4 chunks per thread
#pragma unroll
    for (int wsel = 0; wsel < 2; ++wsel) {
        const float* W = wsel ? Wr : Wl;
#pragma unroll
        for (int i = 0; i < WCH; ++i) {
            int idx = t + 512 * i;
            int r = idx >> 5;
            int c4 = idx & 31;
            float4 v = *(const float4*)(W + (size_t)r * 128 + c4 * 4);
            bf16x4 o;
            o[0] = (__bf16)v.x; o[1] = (__bf16)v.y; o[2] = (__bf16)v.z; o[3] = (__bf16)v.w;
            *(bf16x4*)(Wsm[wsel] + r * 136 + c4 * 4) = o;
        }
    }

    // ---- A staging helper ----
    auto stageA = [&](int buf, int tile) {
        const int rowBase = tile << 7;
        if constexpr (sizeof(AT) == 4) {
#pragma unroll
            for (int i = 0; i < 8; ++i) {
                int idx = t + 512 * i;
                int r = idx >> 5;
                int c4 = idx & 31;
                int grow = rowBase + r;
                if (grow >= M) grow = M - 1;
                float4 v = *(const float4*)((const float*)A + (size_t)grow * 128 + c4 * 4);
                bf16x4 o;
                o[0] = (__bf16)v.x; o[1] = (__bf16)v.y; o[2] = (__bf16)v.z; o[3] = (__bf16)v.w;
                *(bf16x4*)(Asm[buf] + r * 136 + c4 * 4) = o;
            }
        } else {
#pragma unroll
            for (int i = 0; i < 4; ++i) {
                int idx = t + 512 * i;
                int r = idx >> 4;
                int c8 = idx & 15;
                int grow = rowBase + r;
                if (grow >= M) grow = M - 1;
                bf16x8 v = *(const bf16x8*)((const __bf16*)A + (size_t)grow * 128 + c8 * 8);
                *(bf16x8*)(Asm[buf] + r * 136 + c8 * 8) = v;
            }
        }
    };

    const int lane = t & 63;
    const int wid = t >> 6;                      // 0..7
    const int mb = (wid >> 1) * 32;              // row quarter within 128
    const int nbase = (wid & 1) * (DOUT / 2);    // col half
    constexpr int NJ = DOUT / 32;                // 16-col tiles per wave
    const int ln = lane & 15;
    const int qk = lane >> 4;

    float bcol[NJ];
#pragma unroll
    for (int j = 0; j < NJ; ++j) bcol[j] = bias[nbase + j * 16 + ln];

    int tile = blockIdx.x;
    if (tile >= nt) return;
    int buf = 0;
    stageA(0, tile);
    __syncthreads();

    for (; tile < nt; tile += gridDim.x) {
        const int next = tile + gridDim.x;
        if (next < nt) stageA(buf ^ 1, next);    // overlap with compute below

        const int rowBase = tile << 7;
#pragma unroll
        for (int ph = 0; ph < 2; ++ph) {
            f32x4 acc[2][NJ] = {};
#pragma unroll
            for (int ks = 0; ks < 4; ++ks) {
                const int k0 = ks * 32 + qk * 8;
                bf16x8 a0 = *(const bf16x8*)(Asm[buf] + (mb + ln) * 136 + k0);
                bf16x8 a1 = *(const bf16x8*)(Asm[buf] + (mb + 16 + ln) * 136 + k0);
                bf16x8 b[NJ];
#pragma unroll
                for (int j = 0; j < NJ; ++j)
                    b[j] = *(const bf16x8*)(Wsm[ph] + (nbase + j * 16 + ln) * 136 + k0);
#pragma unroll
                for (int j = 0; j < NJ; ++j) {
                    acc[0][j] = __builtin_amdgcn_mfma_f32_16x16x32_bf16(a0, b[j], acc[0][j], 0, 0, 0);
                    acc[1][j] = __builtin_amdgcn_mfma_f32_16x16x32_bf16(a1, b[j], acc[1][j], 0, 0, 0);
                }
            }
            // C/D: col = lane&15, row = (lane>>4)*4 + reg  [m89-verified]
#pragma unroll
            for (int i = 0; i < 2; ++i) {
#pragma unroll
                for (int r = 0; r < 4; ++r) {
                    int grow = rowBase + mb + i * 16 + qk * 4 + r;
                    if (grow >= M) continue;
#pragma unroll
                    for (int j = 0; j < NJ; ++j) {
                        int col = nbase + j * 16 + ln;
                        float v = acc[i][j][r];
                        if (ph) zbuf[(size_t)grow * DOUT + col] = (ZT)(v + bcol[j]);
                        else    ybuf[(size_t)grow * DOUT + col] = (_Float16)v;
                    }
                }
            }
        }
        __syncthreads();   // next-tile stage complete; this buf's reads done
        buf ^= 1;
    }
}

// ---------------------------------------------------------------------------
// Aggregation 128f: one wave per node; 16-lane quads each handle TWO edges
// per iter (stride 8); fp16 rows (256B), 8 f16/lane via uint4; accumulate
// with packed f16 adds -- no unpack, no scale.
// mean + z(bf16) -> ReLU -> LN -> h (bf16).
// ---------------------------------------------------------------------------
__global__ __launch_bounds__(256) void agg_ln128(
    const int* __restrict__ offs, const int* __restrict__ ssrc,
    const _Float16* __restrict__ ybuf,        // [N][128] f16
    const __bf16* __restrict__ zbuf,          // [N][128] bf16
    const float* __restrict__ gamma, const float* __restrict__ beta,
    __bf16* __restrict__ hout, int nNodes) {
    const int lane = threadIdx.x & 63;
    const int qh = lane >> 4;
    const int li = lane & 15;
    const int node = blockIdx.x * 4 + (threadIdx.x >> 6);
    if (node >= nNodes) return;
    const int beg = offs[node], end = offs[node + 1];
    const int deg = end - beg;

    f16x2 pacc[4] = {};
    const int iters = (deg + 7) >> 3;            // 2 edges / quad / iter
    int eA = beg + qh;
    int eB = eA + 4;
    int idxA = 0, idxB = 0;
    if (iters > 0) {
        idxA = ssrc[(eA < end) ? eA : beg];
        idxB = ssrc[(eB < end) ? eB : beg];
    }
    for (int u = 0; u < iters; ++u) {
        const bool va = eA < end;
        const bool vb = eB < end;
        uint4 wa, wb;
        if (va) wa = *(const uint4*)(ybuf + (size_t)idxA * 128 + li * 8);
        if (vb) wb = *(const uint4*)(ybuf + (size_t)idxB * 128 + li * 8);
        int eA2 = eA + 8, eB2 = eB + 8;
        int idxA2 = ssrc[(eA2 < end) ? eA2 : beg];   // prefetch next pair
        int idxB2 = ssrc[(eB2 < end) ? eB2 : beg];
        if (va) {
            pacc[0] += *(const f16x2*)&wa.x;
            pacc[1] += *(const f16x2*)&wa.y;
            pacc[2] += *(const f16x2*)&wa.z;
            pacc[3] += *(const f16x2*)&wa.w;
        }
        if (vb) {
            pacc[0] += *(const f16x2*)&wb.x;
            pacc[1] += *(const f16x2*)&wb.y;
            pacc[2] += *(const f16x2*)&wb.z;
            pacc[3] += *(const f16x2*)&wb.w;
        }
        eA = eA2; eB = eB2; idxA = idxA2; idxB = idxB2;
    }

    // epilogue loads issued before the shuffle chains to overlap latency
    bf16x8 zv = *(const bf16x8*)(zbuf + (size_t)node * 128 + li * 8);
    const float4* g4 = (const float4*)(gamma + li * 8);
    const float4* b4 = (const float4*)(beta + li * 8);
    float4 g0 = g4[0], g1 = g4[1], bb0 = b4[0], bb1 = b4[1];

    // cross-quad reduce on packed regs (2 levels x 4 regs)
#pragma unroll
    for (int m = 0; m < 4; ++m) {
        int w = *(const int*)&pacc[m];
        int w1 = __shfl_xor(w, 16, 64);
        pacc[m] += *(const f16x2*)&w1;
        w = *(const int*)&pacc[m];
        int w2 = __shfl_xor(w, 32, 64);
        pacc[m] += *(const f16x2*)&w2;
    }
    float acc[8];
#pragma unroll
    for (int m = 0; m < 4; ++m) {
        acc[2 * m]     = (float)pacc[m][0];
        acc[2 * m + 1] = (float)pacc[m][1];
    }
    float inv = 1.f / (float)((deg > 1) ? deg : 1);
    float v[8];
#pragma unroll
    for (int m = 0; m < 8; ++m) v[m] = fmaxf(acc[m] * inv + (float)zv[m], 0.f);

    float s = 0.f;
#pragma unroll
    for (int m = 0; m < 8; ++m) s += v[m];
#pragma unroll
    for (int off = 8; off >= 1; off >>= 1) s += __shfl_xor(s, off, 64);
    float mu = s * (1.f / 128.f);
    float d[8], q = 0.f;
#pragma unroll
    for (int m = 0; m < 8; ++m) { d[m] = v[m] - mu; q += d[m] * d[m]; }
#pragma unroll
    for (int off = 8; off >= 1; off >>= 1) q += __shfl_xor(q, off, 64);
    float rstd = rsqrtf(q * (1.f / 128.f) + 1e-5f);

    if (qh == 0) {
        bf16x8 o;
        o[0] = (__bf16)(d[0] * rstd * g0.x + bb0.x);
        o[1] = (__bf16)(d[1] * rstd * g0.y + bb0.y);
        o[2] = (__bf16)(d[2] * rstd * g0.z + bb0.z);
        o[3] = (__bf16)(d[3] * rstd * g0.w + bb0.w);
        o[4] = (__bf16)(d[4] * rstd * g1.x + bb1.x);
        o[5] = (__bf16)(d[5] * rstd * g1.y + bb1.y);
        o[6] = (__bf16)(d[6] * rstd * g1.z + bb1.z);
        o[7] = (__bf16)(d[7] * rstd * g1.w + bb1.w);
        *(bf16x8*)(hout + (size_t)node * 128 + li * 8) = o;
    }
}

// Aggregation 64f (final): 16-lane quads, TWO edges per iter; fp16 rows
// (128B), 4 f16/lane via uint2; packed f16 accumulate; mean + z(fp32) -> f32.
__global__ __launch_bounds__(256) void agg_out64(
    const int* __restrict__ offs, const int* __restrict__ ssrc,
    const _Float16* __restrict__ ybuf,        // [N][64] f16
    const float* __restrict__ zbuf,           // [N][64]
    float* __restrict__ out, int nNodes) {
    const int lane = threadIdx.x & 63;
    const int qh = lane >> 4;
    const int li = lane & 15;
    const int node = blockIdx.x * 4 + (threadIdx.x >> 6);
    if (node >= nNodes) return;
    const int beg = offs[node], end = offs[node + 1];
    const int deg = end - beg;

    f16x2 pacc[2] = {};
    const int iters = (deg + 7) >> 3;            // 2 edges / quad / iter
    int eA = beg + qh;
    int eB = eA + 4;
    int idxA = 0, idxB = 0;
    if (iters > 0) {
        idxA = ssrc[(eA < end) ? eA : beg];
        idxB = ssrc[(eB < end) ? eB : beg];
    }
    for (int u = 0; u < iters; ++u) {
        const bool va = eA < end;
        const bool vb = eB < end;
        uint2 wa, wb;
        if (va) wa = *(const uint2*)(ybuf + (size_t)idxA * 64 + li * 4);
        if (vb) wb = *(const uint2*)(ybuf + (size_t)idxB * 64 + li * 4);
        int eA2 = eA + 8, eB2 = eB + 8;
        int idxA2 = ssrc[(eA2 < end) ? eA2 : beg];
        int idxB2 = ssrc[(eB2 < end) ? eB2 : beg];
        if (va) {
            pacc[0] += *(const f16x2*)&wa.x;
            pacc[1] += *(const f16x2*)&wa.y;
        }
        if (vb) {
            pacc[0] += *(const f16x2*)&wb.x;
            pacc[1] += *(const f16x2*)&wb.y;
        }
        eA = eA2; eB = eB2; idxA = idxA2; idxB = idxB2;
    }

    const float4* z4 = (const float4*)(zbuf + (size_t)node * 64 + li * 4);
    float4 z0 = z4[0];

#pragma unroll
    for (int m = 0; m < 2; ++m) {
        int w = *(const int*)&pacc[m];
        int w1 = __shfl_xor(w, 16, 64);
        pacc[m] += *(const f16x2*)&w1;
        w = *(const int*)&pacc[m];
        int w2 = __shfl_xor(w, 32, 64);
        pacc[m] += *(const f16x2*)&w2;
    }
    if (qh == 0) {
        float inv = 1.f / (float)((deg > 1) ? deg : 1);
        float4 o;
        o.x = (float)pacc[0][0] * inv + z0.x;
        o.y = (float)pacc[0][1] * inv + z0.y;
        o.z = (float)pacc[1][0] * inv + z0.z;
        o.w = (float)pacc[1][1] * inv + z0.w;
        *(float4*)(out + (size_t)node * 64 + li * 4) = o;
    }
}

// ---------------------------------------------------------------------------
extern "C" void kernel_launch(void* const* d_in, const int* in_sizes, int n_in,
                              void* d_out, int out_size, void* d_ws, size_t ws_size,
                              hipStream_t stream) {
    const float* x   = (const float*)d_in[0];
    const int*   ei  = (const int*)d_in[1];
    const float* Wl0 = (const float*)d_in[2];
    const float* Wr0 = (const float*)d_in[3];
    const float* b0  = (const float*)d_in[4];
    const float* Wl1 = (const float*)d_in[5];
    const float* Wr1 = (const float*)d_in[6];
    const float* b1  = (const float*)d_in[7];
    const float* Wl2 = (const float*)d_in[8];
    const float* Wr2 = (const float*)d_in[9];
    const float* b2  = (const float*)d_in[10];
    const float* g0  = (const float*)d_in[11];
    const float* be0 = (const float*)d_in[12];
    const float* g1  = (const float*)d_in[13];
    const float* be1 = (const float*)d_in[14];

    const int N = in_sizes[0] / 128;
    const int E = in_sizes[1] / 2;
    const int* src = ei;
    const int* dst = ei + E;
    float* out = (float*)d_out;

    char* p = (char*)d_ws;
    auto carve = [&](size_t bytes) {
        void* q = (void*)p;
        p += (bytes + 255) & ~(size_t)255;
        return q;
    };
    int*      offs  = (int*)carve(sizeof(int) * (size_t)(N + 1));
    int*      bhist = (int*)carve(sizeof(int) * (size_t)PB_NB);
    int*      bbase = (int*)carve(sizeof(int) * (size_t)PB_NB);
    int*      bcur  = (int*)carve(sizeof(int) * (size_t)PB_NB);
    int*      ssrc  = (int*)carve(sizeof(int) * (size_t)E);
    int2*     part  = (int2*)carve(sizeof(int2) * (size_t)E);
    __bf16*   h     = (__bf16*)carve(sizeof(__bf16) * (size_t)N * 128);
    _Float16* ybuf  = (_Float16*)carve(sizeof(_Float16) * (size_t)N * 128);
    void*     zraw  = carve(sizeof(__bf16) * (size_t)N * 128);  // aliased
    __bf16*   zb    = (__bf16*)zraw;   // LN layers: [N][128] bf16
    float*    zf    = (float*)zraw;    // final layer: [N][64] fp32

    // --- CSR build ---
    (void)hipMemsetAsync(bhist, 0, sizeof(int) * PB_NB, stream);
    const int gridE = (E + PB_CHUNK - 1) / PB_CHUNK;
    coarse_hist<<<gridE, PB_BLOCK, 0, stream>>>(dst, bhist, E);
    coarse_scan<<<1, PB_NB, 0, stream>>>(bhist, bbase, bcur);
    part_scatter<<<gridE, PB_BLOCK, 0, stream>>>(src, dst, bcur, part, E);
    bucket_build<<<PB_NB, 256, 0, stream>>>(part, bbase, offs, ssrc, N, E);

    const int gridNode = (N + 3) / 4;
    const int gridG = 256;               // persistent, 1 block/CU

    // --- Layer 0 (A fp32, converted in staging) ---
    gemm_mfma<128, float, __bf16><<<gridG, 512, 0, stream>>>(x, Wl0, Wr0, b0, ybuf, zb, N);
    agg_ln128<<<gridNode, 256, 0, stream>>>(offs, ssrc, ybuf, zb, g0, be0, h, N);
    // --- Layer 1 ---
    gemm_mfma<128, __bf16, __bf16><<<gridG, 512, 0, stream>>>(h, Wl1, Wr1, b1, ybuf, zb, N);
    agg_ln128<<<gridNode, 256, 0, stream>>>(offs, ssrc, ybuf, zb, g1, be1, h, N);
    // --- Layer 2 (64 feats, z fp32, no LN/ReLU) ---
    gemm_mfma<64, __bf16, float><<<gridG, 512, 0, stream>>>(h, Wl2, Wr2, b2, ybuf, zf, N);
    agg_out64<<<gridNode, 256, 0, stream>>>(offs, ssrc, ybuf, zf, out, N);
}

// Round 10
// 423.506 us; speedup vs baseline: 1.1126x; 1.0002x over previous
//
#include <hip/hip_runtime.h>

// ---------------------------------------------------------------------------
// GraphSAGE 3-layer forward, MI355X.
//   CSR build: coarse 256-bucket histogram -> tiny scan -> part_scatter
//     (bucket-grouped int2 edges, dense writes) -> bucket_build (per-bucket
//     LDS count/scan/scatter -> offs + ssrc). No node-level global atomics.
//   Per layer: bf16 MFMA GEMM, 256 PERSISTENT blocks x 512 threads:
//     Wl+Wr staged into LDS ONCE per block; grid-stride over 128-row A-tiles
//     with T14 async-STAGE split: tile t+1's global loads ISSUED before tile
//     t's MFMA phases, vmcnt-wait + ds_write AFTER compute (loads in flight
//     across the whole ~640cyc compute phase). y f16; z bf16 / fp32.
//   Aggregation: AT STRUCTURAL FLOOR (~70us/dispatch): across
//     bf16/int8/fp16 x 1-2 deep x 4-16 rows/instr, duration pinned 69-71us
//     => ~1 random L2-missing request per edge (MSHR x latency) binding.
//     fp16 ybuf + packed v_pk_add_f16 accumulate (lowest VALU variant kept).
// R16 resubmit (R9 bench was an infra failure: container died, no measure).
// ---------------------------------------------------------------------------

typedef __bf16    bf16x8 __attribute__((ext_vector_type(8)));
typedef __bf16    bf16x4 __attribute__((ext_vector_type(4)));
typedef float     f32x4  __attribute__((ext_vector_type(4)));
typedef _Float16  f16x2  __attribute__((ext_vector_type(2)));

#define PB_SHIFT 9                      // 512 nodes per coarse bucket
#define PB_NB    256                    // covers N <= 131072
#define PB_EPT   8
#define PB_BLOCK 256
#define PB_CHUNK (PB_BLOCK * PB_EPT)    // 2048 edges per block

__global__ __launch_bounds__(PB_BLOCK) void coarse_hist(
    const int* __restrict__ dst, int* __restrict__ bhist, int E) {
    __shared__ int h[PB_NB];
    const int t = threadIdx.x;
    h[t] = 0;
    __syncthreads();
    const int e0 = blockIdx.x * PB_CHUNK + t;
#pragma unroll
    for (int i = 0; i < PB_EPT; ++i) {
        int e = e0 + i * PB_BLOCK;
        if (e < E) atomicAdd(&h[dst[e] >> PB_SHIFT], 1);
    }
    __syncthreads();
    if (h[t]) atomicAdd(&bhist[t], h[t]);
}

__global__ __launch_bounds__(PB_NB) void coarse_scan(
    const int* __restrict__ bhist, int* __restrict__ bbase, int* __restrict__ bcur) {
    __shared__ int sm[PB_NB];
    const int t = threadIdx.x;
    int v = bhist[t];
    sm[t] = v;
    __syncthreads();
    for (int off = 1; off < PB_NB; off <<= 1) {
        int add = (t >= off) ? sm[t - off] : 0;
        __syncthreads();
        sm[t] += add;
        __syncthreads();
    }
    int excl = sm[t] - v;
    bbase[t] = excl;
    bcur[t] = excl;
}

__global__ __launch_bounds__(PB_BLOCK) void part_scatter(
    const int* __restrict__ src, const int* __restrict__ dst,
    int* __restrict__ bcursor, int2* __restrict__ part, int E) {
    __shared__ int hist[PB_NB];
    __shared__ int base[PB_NB];
    const int t = threadIdx.x;
    hist[t] = 0;
    __syncthreads();
    const int e0 = blockIdx.x * PB_CHUNK + t;
    int my_s[PB_EPT], my_d[PB_EPT], my_r[PB_EPT];
#pragma unroll
    for (int i = 0; i < PB_EPT; ++i) {
        int e = e0 + i * PB_BLOCK;
        if (e < E) {
            my_s[i] = src[e];
            my_d[i] = dst[e];
            my_r[i] = atomicAdd(&hist[my_d[i] >> PB_SHIFT], 1);
        }
    }
    __syncthreads();
    {
        int c = hist[t];
        base[t] = c ? atomicAdd(&bcursor[t], c) : 0;
    }
    __syncthreads();
#pragma unroll
    for (int i = 0; i < PB_EPT; ++i) {
        int e = e0 + i * PB_BLOCK;
        if (e < E) {
            int b = my_d[i] >> PB_SHIFT;
            part[base[b] + my_r[i]] = make_int2(my_s[i], my_d[i]);
        }
    }
}

__global__ __launch_bounds__(256) void bucket_build(
    const int2* __restrict__ part, const int* __restrict__ bbase,
    int* __restrict__ offs, int* __restrict__ ssrc, int N, int E) {
    __shared__ int h[512];
    __shared__ int s[512];
    __shared__ int cur[512];
    const int b = blockIdx.x;
    const int t = threadIdx.x;
    const int beg = bbase[b];
    const int end = (b == PB_NB - 1) ? E : bbase[b + 1];

    h[t] = 0; h[t + 256] = 0;
    __syncthreads();
    for (int e = beg + t; e < end; e += 256)
        atomicAdd(&h[part[e].y & 511], 1);
    __syncthreads();
    s[t] = h[t]; s[t + 256] = h[t + 256];
    __syncthreads();
    for (int off = 1; off < 512; off <<= 1) {
        int a0 = (t >= off) ? s[t - off] : 0;
        int i1 = t + 256;
        int a1 = (i1 >= off) ? s[i1 - off] : 0;
        __syncthreads();
        s[t] += a0; s[i1] += a1;
        __syncthreads();
    }
#pragma unroll
    for (int k = 0; k < 2; ++k) {
        int i = t + k * 256;
        int excl = s[i] - h[i];
        cur[i] = excl;
        int node = (b << PB_SHIFT) + i;
        if (node < N) offs[node] = beg + excl;
    }
    if (b == 0 && t == 0) offs[N] = E;
    __syncthreads();
    for (int e = beg + t; e < end; e += 256) {
        int2 sd = part[e];
        int p = atomicAdd(&cur[sd.y & 511], 1);
        ssrc[beg + p] = sd.x;
    }
}

// ---------------------------------------------------------------------------
// Persistent-W MFMA GEMM, T14 async-stage. 512 threads (8 waves), 1 block/CU.
// Prologue: Wl->Wsm[0], Wr->Wsm[1] (bf16, once); A tile 0 staged.
// Loop: issue tile t+1 loads -> compute y & z phases of tile t (HBM latency
// hides under ~640cyc of MFMA + C-stores) -> ds_write tile t+1 -> barrier.
// K=128 LDS-resident (stride 136 bf16 -> 2-way aliasing, free).
// ---------------------------------------------------------------------------
template <int DOUT, typename AT, typename ZT>
__global__ __launch_bounds__(512) void gemm_mfma(
    const AT* __restrict__ A,
    const float* __restrict__ Wl,
    const float* __restrict__ Wr,
    const float* __restrict__ bias,
    _Float16* __restrict__ ybuf,
    ZT*       __restrict__ zbuf,
    int M) {
    __shared__ __bf16 Asm[2][128 * 136];
    __shared__ __bf16 Wsm[2][DOUT * 136];

    const int t = threadIdx.x;
    const int nt = (M + 127) >> 7;               // 128-row tiles

    // ---- stage Wl, Wr once ----
    constexpr int WCH = DOUT * 32 / 512;         // float4 chunks per thread
#pragma unroll
    for (int wsel = 0; wsel < 2; ++wsel) {
        const float* W = wsel ? Wr : Wl;
#pragma unroll
        for (int i = 0; i < WCH; ++i) {
            int idx = t + 512 * i;
            int r = idx >> 5;
            int c4 = idx & 31;
            float4 v = *(const float4*)(W + (size_t)r * 128 + c4 * 4);
            bf16x4 o;
            o[0] = (__bf16)v.x; o[1] = (__bf16)v.y; o[2] = (__bf16)v.z; o[3] = (__bf16)v.w;
            *(bf16x4*)(Wsm[wsel] + r * 136 + c4 * 4) = o;
        }
    }

    float4 aregF[8];      // fp32 path staging regs
    bf16x8 aregB[4];      // bf16 path staging regs

    // ---- issue global loads for a tile (no LDS write, no wait) ----
    auto loadA = [&](int tile) {
        const int rowBase = tile << 7;
        if constexpr (sizeof(AT) == 4) {
#pragma unroll
            for (int i = 0; i < 8; ++i) {
                int idx = t + 512 * i;
                int r = idx >> 5;
                int c4 = idx & 31;
                int grow = rowBase + r;
                if (grow >= M) grow = M - 1;
                aregF[i] = *(const float4*)((const float*)A + (size_t)grow * 128 + c4 * 4);
            }
        } else {
#pragma unroll
            for (int i = 0; i < 4; ++i) {
                int idx = t + 512 * i;
                int r = idx >> 4;
                int c8 = idx & 15;
                int grow = rowBase + r;
                if (grow >= M) grow = M - 1;
                aregB[i] = *(const bf16x8*)((const __bf16*)A + (size_t)grow * 128 + c8 * 8);
            }
        }
    };
    // ---- write staged regs into LDS buffer (compiler inserts vmcnt wait) ----
    auto writeA = [&](int buf) {
        if constexpr (sizeof(AT) == 4) {
#pragma unroll
            for (int i = 0; i < 8; ++i) {
                int idx = t + 512 * i;
                int r = idx >> 5;
                int c4 = idx & 31;
                float4 v = aregF[i];
                bf16x4 o;
                o[0] = (__bf16)v.x; o[1] = (__bf16)v.y; o[2] = (__bf16)v.z; o[3] = (__bf16)v.w;
                *(bf16x4*)(Asm[buf] + r * 136 + c4 * 4) = o;
            }
        } else {
#pragma unroll
            for (int i = 0; i < 4; ++i) {
                int idx = t + 512 * i;
                int r = idx >> 4;
                int c8 = idx & 15;
                *(bf16x8*)(Asm[buf] + r * 136 + c8 * 8) = aregB[i];
            }
        }
    };

    const int lane = t & 63;
    const int wid = t >> 6;                      // 0..7
    const int mb = (wid >> 1) * 32;              // row quarter within 128
    const int nbase = (wid & 1) * (DOUT / 2);    // col half
    constexpr int NJ = DOUT / 32;                // 16-col tiles per wave
    const int ln = lane & 15;
    const int qk = lane >> 4;

    float bcol[NJ];
#pragma unroll
    for (int j = 0; j < NJ; ++j) bcol[j] = bias[nbase + j * 16 + ln];

    int tile = blockIdx.x;
    if (tile >= nt) return;
    int buf = 0;
    loadA(tile);
    writeA(0);
    __syncthreads();

    for (; tile < nt; tile += gridDim.x) {
        const int next = tile + gridDim.x;
        if (next < nt) loadA(next);              // issue early: in flight over compute

        const int rowBase = tile << 7;
#pragma unroll
        for (int ph = 0; ph < 2; ++ph) {
            f32x4 acc[2][NJ] = {};
#pragma unroll
            for (int ks = 0; ks < 4; ++ks) {
                const int k0 = ks * 32 + qk * 8;
                bf16x8 a0 = *(const bf16x8*)(Asm[buf] + (mb + ln) * 136 + k0);
                bf16x8 a1 = *(const bf16x8*)(Asm[buf] + (mb + 16 + ln) * 136 + k0);
                bf16x8 b[NJ];
#pragma unroll
                for (int j = 0; j < NJ; ++j)
                    b[j] = *(const bf16x8*)(Wsm[ph] + (nbase + j * 16 + ln) * 136 + k0);
#pragma unroll
                for (int j = 0; j < NJ; ++j) {
                    acc[0][j] = __builtin_amdgcn_mfma_f32_16x16x32_bf16(a0, b[j], acc[0][j], 0, 0, 0);
                    acc[1][j] = __builtin_amdgcn_mfma_f32_16x16x32_bf16(a1, b[j], acc[1][j], 0, 0, 0);
                }
            }
            // C/D: col = lane&15, row = (lane>>4)*4 + reg  [m89-verified]
#pragma unroll
            for (int i = 0; i < 2; ++i) {
#pragma unroll
                for (int r = 0; r < 4; ++r) {
                    int grow = rowBase + mb + i * 16 + qk * 4 + r;
                    if (grow >= M) continue;
#pragma unroll
                    for (int j = 0; j < NJ; ++j) {
                        int col = nbase + j * 16 + ln;
                        float v = acc[i][j][r];
                        if (ph) zbuf[(size_t)grow * DOUT + col] = (ZT)(v + bcol[j]);
                        else    ybuf[(size_t)grow * DOUT + col] = (_Float16)v;
                    }
                }
            }
        }
        if (next < nt) writeA(buf ^ 1);          // write late: after compute
        __syncthreads();
        buf ^= 1;
    }
}

// ---------------------------------------------------------------------------
// Aggregation 128f: one wave per node; 16-lane quads each handle TWO edges
// per iter (stride 8); fp16 rows (256B), 8 f16/lane via uint4; accumulate
// with packed f16 adds -- no unpack, no scale.
// mean + z(bf16) -> ReLU -> LN -> h (bf16).
// ---------------------------------------------------------------------------
__global__ __launch_bounds__(256) void agg_ln128(
    const int* __restrict__ offs, const int* __restrict__ ssrc,
    const _Float16* __restrict__ ybuf,        // [N][128] f16
    const __bf16* __restrict__ zbuf,          // [N][128] bf16
    const float* __restrict__ gamma, const float* __restrict__ beta,
    __bf16* __restrict__ hout, int nNodes) {
    const int lane = threadIdx.x & 63;
    const int qh = lane >> 4;
    const int li = lane & 15;
    const int node = blockIdx.x * 4 + (threadIdx.x >> 6);
    if (node >= nNodes) return;
    const int beg = offs[node], end = offs[node + 1];
    const int deg = end - beg;

    f16x2 pacc[4] = {};
    const int iters = (deg + 7) >> 3;            // 2 edges / quad / iter
    int eA = beg + qh;
    int eB = eA + 4;
    int idxA = 0, idxB = 0;
    if (iters > 0) {
        idxA = ssrc[(eA < end) ? eA : beg];
        idxB = ssrc[(eB < end) ? eB : beg];
    }
    for (int u = 0; u < iters; ++u) {
        const bool va = eA < end;
        const bool vb = eB < end;
        uint4 wa, wb;
        if (va) wa = *(const uint4*)(ybuf + (size_t)idxA * 128 + li * 8);
        if (vb) wb = *(const uint4*)(ybuf + (size_t)idxB * 128 + li * 8);
        int eA2 = eA + 8, eB2 = eB + 8;
        int idxA2 = ssrc[(eA2 < end) ? eA2 : beg];   // prefetch next pair
        int idxB2 = ssrc[(eB2 < end) ? eB2 : beg];
        if (va) {
            pacc[0] += *(const f16x2*)&wa.x;
            pacc[1] += *(const f16x2*)&wa.y;
            pacc[2] += *(const f16x2*)&wa.z;
            pacc[3] += *(const f16x2*)&wa.w;
        }
        if (vb) {
            pacc[0] += *(const f16x2*)&wb.x;
            pacc[1] += *(const f16x2*)&wb.y;
            pacc[2] += *(const f16x2*)&wb.z;
            pacc[3] += *(const f16x2*)&wb.w;
        }
        eA = eA2; eB = eB2; idxA = idxA2; idxB = idxB2;
    }

    // epilogue loads issued before the shuffle chains to overlap latency
    bf16x8 zv = *(const bf16x8*)(zbuf + (size_t)node * 128 + li * 8);
    const float4* g4 = (const float4*)(gamma + li * 8);
    const float4* b4 = (const float4*)(beta + li * 8);
    float4 g0 = g4[0], g1 = g4[1], bb0 = b4[0], bb1 = b4[1];

    // cross-quad reduce on packed regs (2 levels x 4 regs)
#pragma unroll
    for (int m = 0; m < 4; ++m) {
        int w = *(const int*)&pacc[m];
        int w1 = __shfl_xor(w, 16, 64);
        pacc[m] += *(const f16x2*)&w1;
        w = *(const int*)&pacc[m];
        int w2 = __shfl_xor(w, 32, 64);
        pacc[m] += *(const f16x2*)&w2;
    }
    float acc[8];
#pragma unroll
    for (int m = 0; m < 4; ++m) {
        acc[2 * m]     = (float)pacc[m][0];
        acc[2 * m + 1] = (float)pacc[m][1];
    }
    float inv = 1.f / (float)((deg > 1) ? deg : 1);
    float v[8];
#pragma unroll
    for (int m = 0; m < 8; ++m) v[m] = fmaxf(acc[m] * inv + (float)zv[m], 0.f);

    float s = 0.f;
#pragma unroll
    for (int m = 0; m < 8; ++m) s += v[m];
#pragma unroll
    for (int off = 8; off >= 1; off >>= 1) s += __shfl_xor(s, off, 64);
    float mu = s * (1.f / 128.f);
    float d[8], q = 0.f;
#pragma unroll
    for (int m = 0; m < 8; ++m) { d[m] = v[m] - mu; q += d[m] * d[m]; }
#pragma unroll
    for (int off = 8; off >= 1; off >>= 1) q += __shfl_xor(q, off, 64);
    float rstd = rsqrtf(q * (1.f / 128.f) + 1e-5f);

    if (qh == 0) {
        bf16x8 o;
        o[0] = (__bf16)(d[0] * rstd * g0.x + bb0.x);
        o[1] = (__bf16)(d[1] * rstd * g0.y + bb0.y);
        o[2] = (__bf16)(d[2] * rstd * g0.z + bb0.z);
        o[3] = (__bf16)(d[3] * rstd * g0.w + bb0.w);
        o[4] = (__bf16)(d[4] * rstd * g1.x + bb1.x);
        o[5] = (__bf16)(d[5] * rstd * g1.y + bb1.y);
        o[6] = (__bf16)(d[6] * rstd * g1.z + bb1.z);
        o[7] = (__bf16)(d[7] * rstd * g1.w + bb1.w);
        *(bf16x8*)(hout + (size_t)node * 128 + li * 8) = o;
    }
}

// Aggregation 64f (final): 16-lane quads, TWO edges per iter; fp16 rows
// (128B), 4 f16/lane via uint2; packed f16 accumulate; mean + z(fp32) -> f32.
__global__ __launch_bounds__(256) void agg_out64(
    const int* __restrict__ offs, const int* __restrict__ ssrc,
    const _Float16* __restrict__ ybuf,        // [N][64] f16
    const float* __restrict__ zbuf,           // [N][64]
    float* __restrict__ out, int nNodes) {
    const int lane = threadIdx.x & 63;
    const int qh = lane >> 4;
    const int li = lane & 15;
    const int node = blockIdx.x * 4 + (threadIdx.x >> 6);
    if (node >= nNodes) return;
    const int beg = offs[node], end = offs[node + 1];
    const int deg = end - beg;

    f16x2 pacc[2] = {};
    const int iters = (deg + 7) >> 3;            // 2 edges / quad / iter
    int eA = beg + qh;
    int eB = eA + 4;
    int idxA = 0, idxB = 0;
    if (iters > 0) {
        idxA = ssrc[(eA < end) ? eA : beg];
        idxB = ssrc[(eB < end) ? eB : beg];
    }
    for (int u = 0; u < iters; ++u) {
        const bool va = eA < end;
        const bool vb = eB < end;
        uint2 wa, wb;
        if (va) wa = *(const uint2*)(ybuf + (size_t)idxA * 64 + li * 4);
        if (vb) wb = *(const uint2*)(ybuf + (size_t)idxB * 64 + li * 4);
        int eA2 = eA + 8, eB2 = eB + 8;
        int idxA2 = ssrc[(eA2 < end) ? eA2 : beg];
        int idxB2 = ssrc[(eB2 < end) ? eB2 : beg];
        if (va) {
            pacc[0] += *(const f16x2*)&wa.x;
            pacc[1] += *(const f16x2*)&wa.y;
        }
        if (vb) {
            pacc[0] += *(const f16x2*)&wb.x;
            pacc[1] += *(const f16x2*)&wb.y;
        }
        eA = eA2; eB = eB2; idxA = idxA2; idxB = idxB2;
    }

    const float4* z4 = (const float4*)(zbuf + (size_t)node * 64 + li * 4);
    float4 z0 = z4[0];

#pragma unroll
    for (int m = 0; m < 2; ++m) {
        int w = *(const int*)&pacc[m];
        int w1 = __shfl_xor(w, 16, 64);
        pacc[m] += *(const f16x2*)&w1;
        w = *(const int*)&pacc[m];
        int w2 = __shfl_xor(w, 32, 64);
        pacc[m] += *(const f16x2*)&w2;
    }
    if (qh == 0) {
        float inv = 1.f / (float)((deg > 1) ? deg : 1);
        float4 o;
        o.x = (float)pacc[0][0] * inv + z0.x;
        o.y = (float)pacc[0][1] * inv + z0.y;
        o.z = (float)pacc[1][0] * inv + z0.z;
        o.w = (float)pacc[1][1] * inv + z0.w;
        *(float4*)(out + (size_t)node * 64 + li * 4) = o;
    }
}

// ---------------------------------------------------------------------------
extern "C" void kernel_launch(void* const* d_in, const int* in_sizes, int n_in,
                              void* d_out, int out_size, void* d_ws, size_t ws_size,
                              hipStream_t stream) {
    const float* x   = (const float*)d_in[0];
    const int*   ei  = (const int*)d_in[1];
    const float* Wl0 = (const float*)d_in[2];
    const float* Wr0 = (const float*)d_in[3];
    const float* b0  = (const float*)d_in[4];
    const float* Wl1 = (const float*)d_in[5];
    const float* Wr1 = (const float*)d_in[6];
    const float* b1  = (const float*)d_in[7];
    const float* Wl2 = (const float*)d_in[8];
    const float* Wr2 = (const float*)d_in[9];
    const float* b2  = (const float*)d_in[10];
    const float* g0  = (const float*)d_in[11];
    const float* be0 = (const float*)d_in[12];
    const float* g1  = (const float*)d_in[13];
    const float* be1 = (const float*)d_in[14];

    const int N = in_sizes[0] / 128;
    const int E = in_sizes[1] / 2;
    const int* src = ei;
    const int* dst = ei + E;
    float* out = (float*)d_out;

    char* p = (char*)d_ws;
    auto carve = [&](size_t bytes) {
        void* q = (void*)p;
        p += (bytes + 255) & ~(size_t)255;
        return q;
    };
    int*      offs  = (int*)carve(sizeof(int) * (size_t)(N + 1));
    int*      bhist = (int*)carve(sizeof(int) * (size_t)PB_NB);
    int*      bbase = (int*)carve(sizeof(int) * (size_t)PB_NB);
    int*      bcur  = (int*)carve(sizeof(int) * (size_t)PB_NB);
    int*      ssrc  = (int*)carve(sizeof(int) * (size_t)E);
    int2*     part  = (int2*)carve(sizeof(int2) * (size_t)E);
    __bf16*   h     = (__bf16*)carve(sizeof(__bf16) * (size_t)N * 128);
    _Float16* ybuf  = (_Float16*)carve(sizeof(_Float16) * (size_t)N * 128);
    void*     zraw  = carve(sizeof(__bf16) * (size_t)N * 128);  // aliased
    __bf16*   zb    = (__bf16*)zraw;   // LN layers: [N][128] bf16
    float*    zf    = (float*)zraw;    // final layer: [N][64] fp32

    // --- CSR build ---
    (void)hipMemsetAsync(bhist, 0, sizeof(int) * PB_NB, stream);
    const int gridE = (E + PB_CHUNK - 1) / PB_CHUNK;
    coarse_hist<<<gridE, PB_BLOCK, 0, stream>>>(dst, bhist, E);
    coarse_scan<<<1, PB_NB, 0, stream>>>(bhist, bbase, bcur);
    part_scatter<<<gridE, PB_BLOCK, 0, stream>>>(src, dst, bcur, part, E);
    bucket_build<<<PB_NB, 256, 0, stream>>>(part, bbase, offs, ssrc, N, E);

    const int gridNode = (N + 3) / 4;
    const int gridG = 256;               // persistent, 1 block/CU

    // --- Layer 0 (A fp32, converted in staging) ---
    gemm_mfma<128, float, __bf16><<<gridG, 512, 0, stream>>>(x, Wl0, Wr0, b0, ybuf, zb, N);
    agg_ln128<<<gridNode, 256, 0, stream>>>(offs, ssrc, ybuf, zb, g0, be0, h, N);
    // --- Layer 1 ---
    gemm_mfma<128, __bf16, __bf16><<<gridG, 512, 0, stream>>>(h, Wl1, Wr1, b1, ybuf, zb, N);
    agg_ln128<<<gridNode, 256, 0, stream>>>(offs, ssrc, ybuf, zb, g1, be1, h, N);
    // --- Layer 2 (64 feats, z fp32, no LN/ReLU) ---
    gemm_mfma<64, __bf16, float><<<gridG, 512, 0, stream>>>(h, Wl2, Wr2, b2, ybuf, zf, N);
    agg_out64<<<gridNode, 256, 0, stream>>>(offs, ssrc, ybuf, zf, out, N);
}